// Round 2
// baseline (1366.447 us; speedup 1.0000x reference)
//
#include <hip/hip_runtime.h>
#include <math.h>

// ---------------------------------------------------------------------------
// ResCNN_ASP_SpeakerEncoder — fp32 baseline (v1.1: vectorized conv staging)
// Pipeline: prep(Weff + weight transposes) -> GEMM lin1 -> conv1 -> conv2(+2*res)
//           -> conv3(+res) -> GEMM asp1(tanh) -> GEMM asp2 -> softmax(T) partials
//           -> combine -> weighted-stat partials -> final(stats+LN+linear)
// ---------------------------------------------------------------------------

constexpr int B_  = 64;
constexpr int T_  = 3000;
constexpr int NB_ = 257;   // NBINS
constexpr int R_  = B_ * T_;           // 192000 rows
constexpr int NCH = 32;                // softmax T-chunks
constexpr int CHL = 94;                // ceil(3000/32)

// workspace layout (float offsets)
constexpr size_t OFF_BS   = 0;                            // sorted binpoints (82)
constexpr size_t OFF_WEFF = 128;                          // [257][64]
constexpr size_t OFF_W1T  = OFF_WEFF + (size_t)NB_*64;    // [3][64][128]
constexpr size_t OFF_W2T  = OFF_W1T  + 3*64*128;          // [3][128][128]
constexpr size_t OFF_W3T  = OFF_W2T  + 3*128*128;         // [3][128][128]
constexpr size_t OFF_WA1T = OFF_W3T  + 3*128*128;         // [128][64]
constexpr size_t OFF_WA2T = OFF_WA1T + 128*64;            // [64][128]
constexpr size_t SZ_P     = (size_t)B_*NCH*128;
constexpr size_t OFF_PM   = OFF_WA2T + 64*128;
constexpr size_t OFF_PS   = OFF_PM  + SZ_P;
constexpr size_t OFF_MS   = OFF_PS  + SZ_P;               // [B][128]
constexpr size_t OFF_SS   = OFF_MS  + (size_t)B_*128;
constexpr size_t OFF_PCM  = OFF_SS  + (size_t)B_*128;
constexpr size_t OFF_PCQ  = OFF_PCM + SZ_P;
constexpr size_t OFF_H    = OFF_PCQ + SZ_P;               // [R][64]  (h, later v)
constexpr size_t OFF_A    = OFF_H   + (size_t)R_*64;      // [R][128] (i1, later i3)
constexpr size_t OFF_BB   = OFF_A   + (size_t)R_*128;     // [R][128] (s, later logits)

// ---------------------------------------------------------------------------
__global__ void sort_kernel(const float* __restrict__ bp, float* __restrict__ bs) {
    if (threadIdx.x == 0) {
        float tmp[82];
        for (int i = 0; i < 82; ++i) tmp[i] = bp[i];
        for (int i = 1; i < 82; ++i) {             // insertion sort (input ~sorted)
            float key = tmp[i];
            int j = i - 1;
            while (j >= 0 && tmp[j] > key) { tmp[j+1] = tmp[j]; --j; }
            tmp[j+1] = key;
        }
        for (int i = 0; i < 82; ++i) bs[i] = tmp[i];
    }
}

// Builds Weff^T [257][64] and transposed conv/asp weights.
__global__ void prep_kernel(const float* __restrict__ bs, const float* __restrict__ wl1,
                            const float* __restrict__ wc1, const float* __restrict__ wc2,
                            const float* __restrict__ wc3, const float* __restrict__ wa1,
                            const float* __restrict__ wa2,
                            float* __restrict__ weff, float* __restrict__ w1t,
                            float* __restrict__ w2t, float* __restrict__ w3t,
                            float* __restrict__ wa1t, float* __restrict__ wa2t) {
    int gid = blockIdx.x * 256 + threadIdx.x;
    if (gid < NB_*64) {
        int f = gid >> 6, o = gid & 63;
        float acc = (f == 0) ? wl1[o*80] : 0.0f;   // filt[:,:,0] = x[:,:,0]
        for (int n = 1; n < 79; ++n) {             // fb rows 1..78 (row 79 zero)
            float bn = bs[n], bn1 = bs[n+1], bn2 = bs[n+2];
            int ibn  = (int)floorf(bn);
            int ibn1 = (int)floorf(bn1);
            int ibn2 = (int)floorf(bn2);
            float fbv = 0.0f;
            if (f >= ibn && f < ibn1) {
                float d = (bn1-bn)*(bn1-bn);
                fbv = ((float)f - bn) / (d > 0.0f ? d : 1.0f);
            } else if (f >= ibn1 && f < ibn2) {
                float d = (bn2-bn1)*(bn2-bn1);
                fbv = (bn2 - (float)f) / (d > 0.0f ? d : 1.0f);
            }
            acc += wl1[o*80 + n] * fbv;
        }
        weff[gid] = acc;                           // weff[f][o]
        return;
    }
    gid -= NB_*64;
    if (gid < 3*64*128) {                          // w1t[k][ci][c] <- wc1[c][ci][k]
        int k = gid >> 13, ci = (gid >> 7) & 63, c = gid & 127;
        w1t[gid] = wc1[(c*64 + ci)*3 + k];
        return;
    }
    gid -= 3*64*128;
    if (gid < 3*128*128) {
        int k = gid >> 14, ci = (gid >> 7) & 127, c = gid & 127;
        w2t[gid] = wc2[(c*128 + ci)*3 + k];
        return;
    }
    gid -= 3*128*128;
    if (gid < 3*128*128) {
        int k = gid >> 14, ci = (gid >> 7) & 127, c = gid & 127;
        w3t[gid] = wc3[(c*128 + ci)*3 + k];
        return;
    }
    gid -= 3*128*128;
    if (gid < 128*64) {                            // wa1t[ci][o] <- wa1[o][ci]
        int ci = gid >> 6, o = gid & 63;
        wa1t[gid] = wa1[o*128 + ci];
        return;
    }
    gid -= 128*64;
    if (gid < 64*128) {                            // wa2t[ci][o] <- wa2[o][ci]
        int ci = gid >> 7, o = gid & 127;
        wa2t[gid] = wa2[o*64 + ci];
        return;
    }
}

// ---------------------------------------------------------------------------
// Generic tiled GEMM: C[r][n] = act( sum_k A[r][k] * Wt[k][n0+n] + bias[n0+n] )
// tile 128R x 64N, block 256. ACT: 0=none 1=relu 2=tanh
template<int ACT>
__launch_bounds__(256)
__global__ void gemm_rn(const float* __restrict__ A, const float* __restrict__ Wt,
                        const float* __restrict__ bias, float* __restrict__ C,
                        int R, int K, int Ntot) {
    __shared__ float As[128*65];
    __shared__ float Ws[64*64];
    const int tid = threadIdx.x;
    const int ry  = tid >> 3;                 // 0..31, rows ry + 32*i
    const int tx  = tid & 7;                  // 0..7,  cols tx*8 + j
    const int r0  = blockIdx.x * 128;
    const int n0  = blockIdx.y * 64;

    float acc[4][8];
#pragma unroll
    for (int i = 0; i < 4; ++i)
#pragma unroll
        for (int j = 0; j < 8; ++j) acc[i][j] = 0.0f;

    for (int k0 = 0; k0 < K; k0 += 64) {
        const int kc = min(64, K - k0);
        for (int idx = tid; idx < 128*64; idx += 256) {
            int r = idx >> 6, kk = idx & 63;
            if (kk < kc) {
                int rr = r0 + r;
                As[r*65 + kk] = (rr < R) ? A[(size_t)rr*K + k0 + kk] : 0.0f;
            }
        }
        for (int idx = tid; idx < 64*64; idx += 256) {
            int kk = idx >> 6, n = idx & 63;
            if (kk < kc) Ws[kk*64 + n] = Wt[(size_t)(k0 + kk)*Ntot + n0 + n];
        }
        __syncthreads();
        for (int kk = 0; kk < kc; ++kk) {
            float av[4];
#pragma unroll
            for (int i = 0; i < 4; ++i) av[i] = As[(ry + 32*i)*65 + kk];
            const float4 w0 = *(const float4*)&Ws[kk*64 + tx*8];
            const float4 w1 = *(const float4*)&Ws[kk*64 + tx*8 + 4];
#pragma unroll
            for (int i = 0; i < 4; ++i) {
                acc[i][0] += av[i]*w0.x; acc[i][1] += av[i]*w0.y;
                acc[i][2] += av[i]*w0.z; acc[i][3] += av[i]*w0.w;
                acc[i][4] += av[i]*w1.x; acc[i][5] += av[i]*w1.y;
                acc[i][6] += av[i]*w1.z; acc[i][7] += av[i]*w1.w;
            }
        }
        __syncthreads();
    }

    float bv[8];
#pragma unroll
    for (int j = 0; j < 8; ++j) bv[j] = bias[n0 + tx*8 + j];
#pragma unroll
    for (int i = 0; i < 4; ++i) {
        int rr = r0 + ry + 32*i;
        if (rr < R) {
            float o[8];
#pragma unroll
            for (int j = 0; j < 8; ++j) {
                float v = acc[i][j] + bv[j];
                if (ACT == 1) v = fmaxf(v, 0.0f);
                if (ACT == 2) v = tanhf(v);
                o[j] = v;
            }
            float* cp = &C[(size_t)rr*Ntot + n0 + tx*8];
            *(float4*)cp       = make_float4(o[0], o[1], o[2], o[3]);
            *(float4*)(cp + 4) = make_float4(o[4], o[5], o[6], o[7]);
        }
    }
}

// ---------------------------------------------------------------------------
// Dilated conv (K=3), 128 out channels. Input X: (B,T,CIN) t-major.
// Wt: [3][CIN][128]. RES: 0 none; 1 out=conv+center; 2 out=conv+2*center.
template<int CIN, int DIL, int RES>
__launch_bounds__(256)
__global__ void dconv_kernel(const float* __restrict__ X, const float* __restrict__ Wt,
                             const float* __restrict__ bias, float* __restrict__ Y) {
    constexpr int HS   = 64 + 2*DIL;
    constexpr int HSTR = CIN + 4;             // floats; HSTR%4==0 keeps 16B align
    __shared__ float hs[HS*HSTR];
    __shared__ float wk[32*128];
    const int tid = threadIdx.x;
    const int ty  = tid >> 4;                 // 0..15, t_local = ty + 16*i
    const int tx  = tid & 15;                 // 0..15, c = tx*8 + j
    const int t0  = blockIdx.x * 64;
    const int b   = blockIdx.y;

    // vectorized halo stage: CIN%4==0 so each float4 stays within one t-row
    for (int idx = tid; idx < HS*CIN/4; idx += 256) {
        int e  = idx * 4;
        int r  = e / CIN, ci = e % CIN;
        int t  = t0 - DIL + r;
        float4 v = make_float4(0.f, 0.f, 0.f, 0.f);
        if (t >= 0 && t < T_) v = *(const float4*)&X[((size_t)b*T_ + t)*CIN + ci];
        *(float4*)&hs[r*HSTR + ci] = v;
    }

    float acc[4][8];
#pragma unroll
    for (int i = 0; i < 4; ++i)
#pragma unroll
        for (int j = 0; j < 8; ++j) acc[i][j] = 0.0f;

    for (int k = 0; k < 3; ++k) {
        for (int cib = 0; cib < CIN; cib += 32) {
            __syncthreads();                  // protect hs stage (1st) / wk reuse
            for (int idx = tid; idx < 32*128; idx += 256)
                wk[idx] = Wt[(size_t)(k*CIN + cib)*128 + idx];
            __syncthreads();
#pragma unroll 4
            for (int ci = 0; ci < 32; ++ci) {
                float av[4];
#pragma unroll
                for (int i = 0; i < 4; ++i)
                    av[i] = hs[(ty + 16*i + k*DIL)*HSTR + cib + ci];
                const float4 w0 = *(const float4*)&wk[ci*128 + tx*8];
                const float4 w1 = *(const float4*)&wk[ci*128 + tx*8 + 4];
#pragma unroll
                for (int i = 0; i < 4; ++i) {
                    acc[i][0] += av[i]*w0.x; acc[i][1] += av[i]*w0.y;
                    acc[i][2] += av[i]*w0.z; acc[i][3] += av[i]*w0.w;
                    acc[i][4] += av[i]*w1.x; acc[i][5] += av[i]*w1.y;
                    acc[i][6] += av[i]*w1.z; acc[i][7] += av[i]*w1.w;
                }
            }
        }
    }

    float bv[8];
#pragma unroll
    for (int j = 0; j < 8; ++j) bv[j] = bias[tx*8 + j];
#pragma unroll
    for (int i = 0; i < 4; ++i) {
        int tl = ty + 16*i;
        int t  = t0 + tl;
        if (t < T_) {
            float o[8];
#pragma unroll
            for (int j = 0; j < 8; ++j) {
                float v = acc[i][j] + bv[j];
                if (RES >= 1) {
                    float cen = hs[(tl + DIL)*HSTR + tx*8 + j];
                    v += (RES == 2) ? 2.0f*cen : cen;
                }
                o[j] = v;
            }
            float* yp = &Y[((size_t)b*T_ + t)*128 + tx*8];
            *(float4*)yp       = make_float4(o[0], o[1], o[2], o[3]);
            *(float4*)(yp + 4) = make_float4(o[4], o[5], o[6], o[7]);
        }
    }
}

// ---------------------------------------------------------------------------
// softmax over T, chunked online partials. a: (B,T,128)
__global__ void sm_pass_a(const float* __restrict__ a, float* __restrict__ pm,
                          float* __restrict__ ps) {
    const int c = threadIdx.x, ch = blockIdx.x, b = blockIdx.y;
    const int ts = ch * CHL, te = min(T_, ts + CHL);
    float m = -INFINITY, s = 0.0f;
    for (int t = ts; t < te; ++t) {
        float v = a[((size_t)b*T_ + t)*128 + c];
        float nm = fmaxf(m, v);
        s = s*expf(m - nm) + expf(v - nm);
        m = nm;
    }
    pm[((size_t)b*NCH + ch)*128 + c] = m;
    ps[((size_t)b*NCH + ch)*128 + c] = s;
}

__global__ void sm_pass_b(const float* __restrict__ pm, const float* __restrict__ ps,
                          float* __restrict__ Ms, float* __restrict__ Ss) {
    const int c = threadIdx.x, b = blockIdx.x;
    float M = -INFINITY;
    for (int ch = 0; ch < NCH; ++ch) M = fmaxf(M, pm[((size_t)b*NCH + ch)*128 + c]);
    float S = 0.0f;
    for (int ch = 0; ch < NCH; ++ch)
        S += ps[((size_t)b*NCH + ch)*128 + c] * expf(pm[((size_t)b*NCH + ch)*128 + c] - M);
    Ms[b*128 + c] = M;
    Ss[b*128 + c] = S;
}

__global__ void sm_pass_c(const float* __restrict__ a, const float* __restrict__ i3,
                          const float* __restrict__ Ms, float* __restrict__ pcm,
                          float* __restrict__ pcq) {
    const int c = threadIdx.x, ch = blockIdx.x, b = blockIdx.y;
    const int ts = ch * CHL, te = min(T_, ts + CHL);
    const float M = Ms[b*128 + c];
    float am = 0.0f, aq = 0.0f;
    for (int t = ts; t < te; ++t) {
        float p = expf(a[((size_t)b*T_ + t)*128 + c] - M);
        float x = i3[((size_t)b*T_ + t)*128 + c];
        am += p*x;
        aq += p*x*x;
    }
    pcm[((size_t)b*NCH + ch)*128 + c] = am;
    pcq[((size_t)b*NCH + ch)*128 + c] = aq;
}

// stats -> layernorm(256) -> linear 256->512
__global__ void final_kernel(const float* __restrict__ pcm, const float* __restrict__ pcq,
                             const float* __restrict__ Ss, const float* __restrict__ gamma,
                             const float* __restrict__ beta, const float* __restrict__ w2,
                             const float* __restrict__ b2, float* __restrict__ out) {
    __shared__ float row[256];
    __shared__ float nrm[256];
    __shared__ float red[8];
    const int tid = threadIdx.x, b = blockIdx.x;
    if (tid < 128) {
        float sm = 0.0f, sq = 0.0f;
        for (int ch = 0; ch < NCH; ++ch) {
            sm += pcm[((size_t)b*NCH + ch)*128 + tid];
            sq += pcq[((size_t)b*NCH + ch)*128 + tid];
        }
        float S = Ss[b*128 + tid];
        float mean = sm / S;
        float q    = sq / S;
        float resid = q - mean*mean;
        float stdv  = sqrtf(fmaxf(resid, 1e-9f));
        row[tid]       = mean;
        row[128 + tid] = stdv;
    }
    __syncthreads();
    float v  = row[tid];
    float s1 = v, s2 = v*v;
    for (int off = 32; off >= 1; off >>= 1) {
        s1 += __shfl_down(s1, off, 64);
        s2 += __shfl_down(s2, off, 64);
    }
    if ((tid & 63) == 0) { red[tid >> 6] = s1; red[4 + (tid >> 6)] = s2; }
    __syncthreads();
    float S1 = red[0] + red[1] + red[2] + red[3];
    float S2 = red[4] + red[5] + red[6] + red[7];
    float mu  = S1 / 256.0f;
    float var = S2 / 256.0f - mu*mu;
    float inv = 1.0f / sqrtf(var + 1e-5f);
    nrm[tid] = (v - mu)*inv*gamma[tid] + beta[tid];
    __syncthreads();
#pragma unroll
    for (int oo = 0; oo < 2; ++oo) {
        int o = tid + oo*256;
        float acc = b2[o];
        const float4* wr = (const float4*)&w2[(size_t)o*256];
        for (int j = 0; j < 64; ++j) {
            float4 w = wr[j];
            acc += w.x*nrm[j*4] + w.y*nrm[j*4+1] + w.z*nrm[j*4+2] + w.w*nrm[j*4+3];
        }
        out[(size_t)b*512 + o] = acc;
    }
}

// ---------------------------------------------------------------------------
extern "C" void kernel_launch(void* const* d_in, const int* in_sizes, int n_in,
                              void* d_out, int out_size, void* d_ws, size_t ws_size,
                              hipStream_t stream) {
    const float* x      = (const float*)d_in[0];
    const float* bp     = (const float*)d_in[1];
    const float* w_lin1 = (const float*)d_in[2];
    const float* b_lin1 = (const float*)d_in[3];
    const float* wc1    = (const float*)d_in[4];
    const float* bc1    = (const float*)d_in[5];
    const float* wc2    = (const float*)d_in[6];
    const float* bc2    = (const float*)d_in[7];
    const float* wc3    = (const float*)d_in[8];
    const float* bc3    = (const float*)d_in[9];
    const float* wa1    = (const float*)d_in[10];
    const float* ba1    = (const float*)d_in[11];
    const float* wa2    = (const float*)d_in[12];
    const float* ba2    = (const float*)d_in[13];
    const float* gamma  = (const float*)d_in[14];
    const float* beta   = (const float*)d_in[15];
    const float* wl2    = (const float*)d_in[16];
    const float* bl2    = (const float*)d_in[17];

    float* ws   = (float*)d_ws;
    float* bs   = ws + OFF_BS;
    float* weff = ws + OFF_WEFF;
    float* w1t  = ws + OFF_W1T;
    float* w2t  = ws + OFF_W2T;
    float* w3t  = ws + OFF_W3T;
    float* wa1t = ws + OFF_WA1T;
    float* wa2t = ws + OFF_WA2T;
    float* pm   = ws + OFF_PM;
    float* ps   = ws + OFF_PS;
    float* Ms   = ws + OFF_MS;
    float* Ss   = ws + OFF_SS;
    float* pcm  = ws + OFF_PCM;
    float* pcq  = ws + OFF_PCQ;
    float* h    = ws + OFF_H;    // h, then v
    float* bufA = ws + OFF_A;    // i1, then i3
    float* bufB = ws + OFF_BB;   // s,  then logits

    sort_kernel<<<dim3(1), dim3(64), 0, stream>>>(bp, bs);
    prep_kernel<<<dim3(609), dim3(256), 0, stream>>>(bs, w_lin1, wc1, wc2, wc3, wa1, wa2,
                                                     weff, w1t, w2t, w3t, wa1t, wa2t);
    // h = relu(x @ Weff^T + b_lin1)
    gemm_rn<1><<<dim3(R_/128, 1), dim3(256), 0, stream>>>(x, weff, b_lin1, h, R_, NB_, 64);
    // i1 = conv1(h) + b
    dconv_kernel<64, 2, 0><<<dim3(47, B_), dim3(256), 0, stream>>>(h, w1t, bc1, bufA);
    // s = i1 + i2 = conv2(i1) + b + 2*i1
    dconv_kernel<128, 3, 2><<<dim3(47, B_), dim3(256), 0, stream>>>(bufA, w2t, bc2, bufB);
    // i3 = conv3(s) + b + s
    dconv_kernel<128, 4, 1><<<dim3(47, B_), dim3(256), 0, stream>>>(bufB, w3t, bc3, bufA);
    // v = tanh(i3 @ wa1^T + ba1)   (into h buffer)
    gemm_rn<2><<<dim3(R_/128, 1), dim3(256), 0, stream>>>(bufA, wa1t, ba1, h, R_, 128, 64);
    // logits = v @ wa2^T + ba2     (into bufB)
    gemm_rn<0><<<dim3(R_/128, 2), dim3(256), 0, stream>>>(h, wa2t, ba2, bufB, R_, 64, 128);
    // softmax over T + weighted stats
    sm_pass_a<<<dim3(NCH, B_), dim3(128), 0, stream>>>(bufB, pm, ps);
    sm_pass_b<<<dim3(B_), dim3(128), 0, stream>>>(pm, ps, Ms, Ss);
    sm_pass_c<<<dim3(NCH, B_), dim3(128), 0, stream>>>(bufB, bufA, Ms, pcm, pcq);
    final_kernel<<<dim3(B_), dim3(256), 0, stream>>>(pcm, pcq, Ss, gamma, beta, wl2, bl2,
                                                     (float*)d_out);
}

// Round 3
// 904.557 us; speedup vs baseline: 1.5106x; 1.5106x over previous
//
#include <hip/hip_runtime.h>
#include <math.h>

// ---------------------------------------------------------------------------
// ResCNN_ASP_SpeakerEncoder — v2: dilated convs via split-bf16 (3-pass) MFMA.
// conv error ~2^-16 relative => absmax should match fp32 baseline (~2e-3).
// ---------------------------------------------------------------------------

constexpr int B_  = 64;
constexpr int T_  = 3000;
constexpr int NB_ = 257;   // NBINS
constexpr int R_  = B_ * T_;           // 192000 rows
constexpr int NCH = 32;                // softmax T-chunks
constexpr int CHL = 94;                // ceil(3000/32)

// workspace layout (float offsets) — identical total footprint to v1
constexpr size_t OFF_BS   = 0;                            // sorted binpoints (82)
constexpr size_t OFF_WEFF = 128;                          // fp32 [257][64]
constexpr size_t OFF_W1   = OFF_WEFF + (size_t)NB_*64;    // ushort hi[3*128*64] + lo
constexpr size_t OFF_W2   = OFF_W1  + 3*64*128;           // ushort hi[3*128*128] + lo
constexpr size_t OFF_W3   = OFF_W2  + 3*128*128;
constexpr size_t OFF_WA1T = OFF_W3  + 3*128*128;          // fp32 [128][64]
constexpr size_t OFF_WA2T = OFF_WA1T + 128*64;            // fp32 [64][128]
constexpr size_t SZ_P     = (size_t)B_*NCH*128;
constexpr size_t OFF_PM   = OFF_WA2T + 64*128;
constexpr size_t OFF_PS   = OFF_PM  + SZ_P;
constexpr size_t OFF_MS   = OFF_PS  + SZ_P;               // [B][128]
constexpr size_t OFF_SS   = OFF_MS  + (size_t)B_*128;
constexpr size_t OFF_PCM  = OFF_SS  + (size_t)B_*128;
constexpr size_t OFF_PCQ  = OFF_PCM + SZ_P;
constexpr size_t OFF_H    = OFF_PCQ + SZ_P;               // [R][64]  (h, later v)
constexpr size_t OFF_A    = OFF_H   + (size_t)R_*64;      // [R][128] (i1, later i3)
constexpr size_t OFF_BB   = OFF_A   + (size_t)R_*128;     // [R][128] (s, later logits)

typedef __attribute__((ext_vector_type(8))) short  bf16x8;
typedef __attribute__((ext_vector_type(4))) float  f32x4;

__device__ inline unsigned short f2bf(float f) {          // RNE f32->bf16
    unsigned u = __float_as_uint(f);
    unsigned r = u + 0x7FFFu + ((u >> 16) & 1u);
    return (unsigned short)(r >> 16);
}
__device__ inline float bf2f(unsigned short h) {
    return __uint_as_float(((unsigned)h) << 16);
}

// ---------------------------------------------------------------------------
__global__ void sort_kernel(const float* __restrict__ bp, float* __restrict__ bs) {
    if (threadIdx.x == 0) {
        float tmp[82];
        for (int i = 0; i < 82; ++i) tmp[i] = bp[i];
        for (int i = 1; i < 82; ++i) {
            float key = tmp[i];
            int j = i - 1;
            while (j >= 0 && tmp[j] > key) { tmp[j+1] = tmp[j]; --j; }
            tmp[j+1] = key;
        }
        for (int i = 0; i < 82; ++i) bs[i] = tmp[i];
    }
}

// Builds Weff^T [257][64] fp32, conv weights as bf16 hi/lo in [k][c][ci],
// and fp32 transposes for the ASP linears.
__global__ void prep_kernel(const float* __restrict__ bs, const float* __restrict__ wl1,
                            const float* __restrict__ wc1, const float* __restrict__ wc2,
                            const float* __restrict__ wc3, const float* __restrict__ wa1,
                            const float* __restrict__ wa2,
                            float* __restrict__ weff,
                            unsigned short* __restrict__ w1h, unsigned short* __restrict__ w1l,
                            unsigned short* __restrict__ w2h, unsigned short* __restrict__ w2l,
                            unsigned short* __restrict__ w3h, unsigned short* __restrict__ w3l,
                            float* __restrict__ wa1t, float* __restrict__ wa2t) {
    int gid = blockIdx.x * 256 + threadIdx.x;
    if (gid < NB_*64) {
        int f = gid >> 6, o = gid & 63;
        float acc = (f == 0) ? wl1[o*80] : 0.0f;   // filt[:,:,0] = x[:,:,0]
        for (int n = 1; n < 79; ++n) {             // fb rows 1..78 (row 79 zero)
            float bn = bs[n], bn1 = bs[n+1], bn2 = bs[n+2];
            int ibn  = (int)floorf(bn);
            int ibn1 = (int)floorf(bn1);
            int ibn2 = (int)floorf(bn2);
            float fbv = 0.0f;
            if (f >= ibn && f < ibn1) {
                float d = (bn1-bn)*(bn1-bn);
                fbv = ((float)f - bn) / (d > 0.0f ? d : 1.0f);
            } else if (f >= ibn1 && f < ibn2) {
                float d = (bn2-bn1)*(bn2-bn1);
                fbv = (bn2 - (float)f) / (d > 0.0f ? d : 1.0f);
            }
            acc += wl1[o*80 + n] * fbv;
        }
        weff[gid] = acc;                           // weff[f][o]
        return;
    }
    gid -= NB_*64;
    if (gid < 3*128*64) {                          // conv1: [k][c][ci=64]
        int k = gid / (128*64), rem = gid % (128*64);
        int c = rem >> 6, ci = rem & 63;
        float v = wc1[(c*64 + ci)*3 + k];
        unsigned short h = f2bf(v);
        w1h[gid] = h; w1l[gid] = f2bf(v - bf2f(h));
        return;
    }
    gid -= 3*128*64;
    if (gid < 3*128*128) {                         // conv2: [k][c][ci=128]
        int k = gid / (128*128), rem = gid % (128*128);
        int c = rem >> 7, ci = rem & 127;
        float v = wc2[(c*128 + ci)*3 + k];
        unsigned short h = f2bf(v);
        w2h[gid] = h; w2l[gid] = f2bf(v - bf2f(h));
        return;
    }
    gid -= 3*128*128;
    if (gid < 3*128*128) {                         // conv3
        int k = gid / (128*128), rem = gid % (128*128);
        int c = rem >> 7, ci = rem & 127;
        float v = wc3[(c*128 + ci)*3 + k];
        unsigned short h = f2bf(v);
        w3h[gid] = h; w3l[gid] = f2bf(v - bf2f(h));
        return;
    }
    gid -= 3*128*128;
    if (gid < 128*64) {                            // wa1t[ci][o] <- wa1[o][ci]
        int ci = gid >> 6, o = gid & 63;
        wa1t[gid] = wa1[o*128 + ci];
        return;
    }
    gid -= 128*64;
    if (gid < 64*128) {                            // wa2t[ci][o] <- wa2[o][ci]
        int ci = gid >> 7, o = gid & 127;
        wa2t[gid] = wa2[o*64 + ci];
        return;
    }
}

// ---------------------------------------------------------------------------
// Generic tiled GEMM (fp32): C[r][n] = act( A[r][:]·Wt[:][n] + bias[n] )
template<int ACT>
__launch_bounds__(256)
__global__ void gemm_rn(const float* __restrict__ A, const float* __restrict__ Wt,
                        const float* __restrict__ bias, float* __restrict__ C,
                        int R, int K, int Ntot) {
    __shared__ float As[128*65];
    __shared__ float Ws[64*64];
    const int tid = threadIdx.x;
    const int ry  = tid >> 3;
    const int tx  = tid & 7;
    const int r0  = blockIdx.x * 128;
    const int n0  = blockIdx.y * 64;

    float acc[4][8];
#pragma unroll
    for (int i = 0; i < 4; ++i)
#pragma unroll
        for (int j = 0; j < 8; ++j) acc[i][j] = 0.0f;

    for (int k0 = 0; k0 < K; k0 += 64) {
        const int kc = min(64, K - k0);
        for (int idx = tid; idx < 128*64; idx += 256) {
            int r = idx >> 6, kk = idx & 63;
            if (kk < kc) {
                int rr = r0 + r;
                As[r*65 + kk] = (rr < R) ? A[(size_t)rr*K + k0 + kk] : 0.0f;
            }
        }
        for (int idx = tid; idx < 64*64; idx += 256) {
            int kk = idx >> 6, n = idx & 63;
            if (kk < kc) Ws[kk*64 + n] = Wt[(size_t)(k0 + kk)*Ntot + n0 + n];
        }
        __syncthreads();
        for (int kk = 0; kk < kc; ++kk) {
            float av[4];
#pragma unroll
            for (int i = 0; i < 4; ++i) av[i] = As[(ry + 32*i)*65 + kk];
            const float4 w0 = *(const float4*)&Ws[kk*64 + tx*8];
            const float4 w1 = *(const float4*)&Ws[kk*64 + tx*8 + 4];
#pragma unroll
            for (int i = 0; i < 4; ++i) {
                acc[i][0] += av[i]*w0.x; acc[i][1] += av[i]*w0.y;
                acc[i][2] += av[i]*w0.z; acc[i][3] += av[i]*w0.w;
                acc[i][4] += av[i]*w1.x; acc[i][5] += av[i]*w1.y;
                acc[i][6] += av[i]*w1.z; acc[i][7] += av[i]*w1.w;
            }
        }
        __syncthreads();
    }

    float bv[8];
#pragma unroll
    for (int j = 0; j < 8; ++j) bv[j] = bias[n0 + tx*8 + j];
#pragma unroll
    for (int i = 0; i < 4; ++i) {
        int rr = r0 + ry + 32*i;
        if (rr < R) {
            float o[8];
#pragma unroll
            for (int j = 0; j < 8; ++j) {
                float v = acc[i][j] + bv[j];
                if (ACT == 1) v = fmaxf(v, 0.0f);
                if (ACT == 2) v = tanhf(v);
                o[j] = v;
            }
            float* cp = &C[(size_t)rr*Ntot + n0 + tx*8];
            *(float4*)cp       = make_float4(o[0], o[1], o[2], o[3]);
            *(float4*)(cp + 4) = make_float4(o[4], o[5], o[6], o[7]);
        }
    }
}

// ---------------------------------------------------------------------------
// Dilated conv (K=3) via split-bf16 MFMA. X: (B,T,CIN) fp32. W hi/lo: [k][c][ci]
// bf16. Y: (B,T,128) fp32. Tile: 128 t x 128 c per block, 4 waves (2x2).
// RES: 0 none; 1 out=conv+center; 2 out=conv+2*center (center = X at same t).
template<int CIN, int DIL, int RES>
__launch_bounds__(256)
__global__ void dconv_mfma(const float* __restrict__ X,
                           const unsigned short* __restrict__ Wh,
                           const unsigned short* __restrict__ Wl,
                           const float* __restrict__ bias, float* __restrict__ Y) {
    constexpr int TT = 128;
    constexpr int HS = TT + 2*DIL;
    __shared__ __align__(16) unsigned short hsh[HS*CIN];
    __shared__ __align__(16) unsigned short hsl[HS*CIN];

    const int tid  = threadIdx.x;
    const int lane = tid & 63;
    const int wid  = tid >> 6;
    const int wy   = wid >> 1;            // 0..1: rows wy*64 + m*16
    const int wx   = wid & 1;             // 0..1: cols wx*64 + n*16
    const int l16  = lane & 15;
    const int l4   = lane >> 4;           // k-octet
    const int t0   = blockIdx.x * TT;
    const int b    = blockIdx.y;

    // ---- stage X tile -> bf16 hi/lo in LDS, XOR-swizzled rows (G4 fix) ----
    for (int idx = tid; idx < HS*CIN/4; idx += 256) {
        int e  = idx << 2;
        int r  = e / CIN, ci = e % CIN;
        int t  = t0 - DIL + r;
        float4 v = make_float4(0.f, 0.f, 0.f, 0.f);
        if (t >= 0 && t < T_) v = *(const float4*)&X[((size_t)b*T_ + t)*CIN + ci];
        unsigned short h0 = f2bf(v.x), h1 = f2bf(v.y), h2 = f2bf(v.z), h3 = f2bf(v.w);
        unsigned short g0 = f2bf(v.x - bf2f(h0)), g1 = f2bf(v.y - bf2f(h1));
        unsigned short g2 = f2bf(v.z - bf2f(h2)), g3 = f2bf(v.w - bf2f(h3));
        unsigned byte = ((unsigned)(r*CIN + ci))*2u ^ ((unsigned)((r & 7) << 4));
        uint2 ph; ph.x = (unsigned)h0 | ((unsigned)h1 << 16); ph.y = (unsigned)h2 | ((unsigned)h3 << 16);
        uint2 pl; pl.x = (unsigned)g0 | ((unsigned)g1 << 16); pl.y = (unsigned)g2 | ((unsigned)g3 << 16);
        *(uint2*)((char*)hsh + byte) = ph;
        *(uint2*)((char*)hsl + byte) = pl;
    }
    __syncthreads();

    f32x4 acc[4][4];
    const f32x4 z = {0.f, 0.f, 0.f, 0.f};
#pragma unroll
    for (int m = 0; m < 4; ++m)
#pragma unroll
        for (int n = 0; n < 4; ++n) acc[m][n] = z;

    for (int k = 0; k < 3; ++k) {
#pragma unroll
        for (int cib = 0; cib < CIN; cib += 32) {
            bf16x8 bh[4], bl[4];
#pragma unroll
            for (int n = 0; n < 4; ++n) {              // B[k=ci][col=c]
                int c = wx*64 + n*16 + l16;
                size_t off = ((size_t)(k*128 + c))*CIN + cib + l4*8;
                bh[n] = *(const bf16x8*)(Wh + off);
                bl[n] = *(const bf16x8*)(Wl + off);
            }
            bf16x8 ah[4], al[4];
#pragma unroll
            for (int m = 0; m < 4; ++m) {              // A[row=t][k=ci]
                int r = wy*64 + m*16 + l16 + k*DIL;
                unsigned byte = ((unsigned)(r*CIN + cib + l4*8))*2u
                              ^ ((unsigned)((r & 7) << 4));
                ah[m] = *(const bf16x8*)((const char*)hsh + byte);
                al[m] = *(const bf16x8*)((const char*)hsl + byte);
            }
#pragma unroll
            for (int m = 0; m < 4; ++m)
#pragma unroll
                for (int n = 0; n < 4; ++n) {
                    acc[m][n] = __builtin_amdgcn_mfma_f32_16x16x32_bf16(ah[m], bh[n], acc[m][n], 0, 0, 0);
                    acc[m][n] = __builtin_amdgcn_mfma_f32_16x16x32_bf16(ah[m], bl[n], acc[m][n], 0, 0, 0);
                    acc[m][n] = __builtin_amdgcn_mfma_f32_16x16x32_bf16(al[m], bh[n], acc[m][n], 0, 0, 0);
                }
        }
    }

    // ---- epilogue: bias, residual center (hi+lo reconstruct), store fp32 ----
#pragma unroll
    for (int m = 0; m < 4; ++m) {
        int tl_base = wy*64 + m*16 + l4*4;             // C/D row = (lane>>4)*4+reg
#pragma unroll
        for (int n = 0; n < 4; ++n) {
            int c = wx*64 + n*16 + l16;                // C/D col = lane&15
            float bv = bias[c];
#pragma unroll
            for (int rg = 0; rg < 4; ++rg) {
                int tl = tl_base + rg;
                int t  = t0 + tl;
                if (t < T_) {
                    float v = acc[m][n][rg] + bv;
                    if (RES >= 1) {
                        int r = tl + DIL;
                        unsigned byte = ((unsigned)(r*CIN + c))*2u
                                      ^ ((unsigned)((r & 7) << 4));
                        float cen = bf2f(*(const unsigned short*)((const char*)hsh + byte))
                                  + bf2f(*(const unsigned short*)((const char*)hsl + byte));
                        v += (RES == 2) ? 2.0f*cen : cen;
                    }
                    Y[((size_t)b*T_ + t)*128 + c] = v;
                }
            }
        }
    }
}

// ---------------------------------------------------------------------------
// softmax over T, chunked online partials. a: (B,T,128)
__global__ void sm_pass_a(const float* __restrict__ a, float* __restrict__ pm,
                          float* __restrict__ ps) {
    const int c = threadIdx.x, ch = blockIdx.x, b = blockIdx.y;
    const int ts = ch * CHL, te = min(T_, ts + CHL);
    float m = -INFINITY, s = 0.0f;
    for (int t = ts; t < te; ++t) {
        float v = a[((size_t)b*T_ + t)*128 + c];
        float nm = fmaxf(m, v);
        s = s*expf(m - nm) + expf(v - nm);
        m = nm;
    }
    pm[((size_t)b*NCH + ch)*128 + c] = m;
    ps[((size_t)b*NCH + ch)*128 + c] = s;
}

__global__ void sm_pass_b(const float* __restrict__ pm, const float* __restrict__ ps,
                          float* __restrict__ Ms, float* __restrict__ Ss) {
    const int c = threadIdx.x, b = blockIdx.x;
    float M = -INFINITY;
    for (int ch = 0; ch < NCH; ++ch) M = fmaxf(M, pm[((size_t)b*NCH + ch)*128 + c]);
    float S = 0.0f;
    for (int ch = 0; ch < NCH; ++ch)
        S += ps[((size_t)b*NCH + ch)*128 + c] * expf(pm[((size_t)b*NCH + ch)*128 + c] - M);
    Ms[b*128 + c] = M;
    Ss[b*128 + c] = S;
}

__global__ void sm_pass_c(const float* __restrict__ a, const float* __restrict__ i3,
                          const float* __restrict__ Ms, float* __restrict__ pcm,
                          float* __restrict__ pcq) {
    const int c = threadIdx.x, ch = blockIdx.x, b = blockIdx.y;
    const int ts = ch * CHL, te = min(T_, ts + CHL);
    const float M = Ms[b*128 + c];
    float am = 0.0f, aq = 0.0f;
    for (int t = ts; t < te; ++t) {
        float p = expf(a[((size_t)b*T_ + t)*128 + c] - M);
        float x = i3[((size_t)b*T_ + t)*128 + c];
        am += p*x;
        aq += p*x*x;
    }
    pcm[((size_t)b*NCH + ch)*128 + c] = am;
    pcq[((size_t)b*NCH + ch)*128 + c] = aq;
}

// stats -> layernorm(256) -> linear 256->512
__global__ void final_kernel(const float* __restrict__ pcm, const float* __restrict__ pcq,
                             const float* __restrict__ Ss, const float* __restrict__ gamma,
                             const float* __restrict__ beta, const float* __restrict__ w2,
                             const float* __restrict__ b2, float* __restrict__ out) {
    __shared__ float row[256];
    __shared__ float nrm[256];
    __shared__ float red[8];
    const int tid = threadIdx.x, b = blockIdx.x;
    if (tid < 128) {
        float sm = 0.0f, sq = 0.0f;
        for (int ch = 0; ch < NCH; ++ch) {
            sm += pcm[((size_t)b*NCH + ch)*128 + tid];
            sq += pcq[((size_t)b*NCH + ch)*128 + tid];
        }
        float S = Ss[b*128 + tid];
        float mean = sm / S;
        float q    = sq / S;
        float resid = q - mean*mean;
        float stdv  = sqrtf(fmaxf(resid, 1e-9f));
        row[tid]       = mean;
        row[128 + tid] = stdv;
    }
    __syncthreads();
    float v  = row[tid];
    float s1 = v, s2 = v*v;
    for (int off = 32; off >= 1; off >>= 1) {
        s1 += __shfl_down(s1, off, 64);
        s2 += __shfl_down(s2, off, 64);
    }
    if ((tid & 63) == 0) { red[tid >> 6] = s1; red[4 + (tid >> 6)] = s2; }
    __syncthreads();
    float S1 = red[0] + red[1] + red[2] + red[3];
    float S2 = red[4] + red[5] + red[6] + red[7];
    float mu  = S1 / 256.0f;
    float var = S2 / 256.0f - mu*mu;
    float inv = 1.0f / sqrtf(var + 1e-5f);
    nrm[tid] = (v - mu)*inv*gamma[tid] + beta[tid];
    __syncthreads();
#pragma unroll
    for (int oo = 0; oo < 2; ++oo) {
        int o = tid + oo*256;
        float acc = b2[o];
        const float4* wr = (const float4*)&w2[(size_t)o*256];
        for (int j = 0; j < 64; ++j) {
            float4 w = wr[j];
            acc += w.x*nrm[j*4] + w.y*nrm[j*4+1] + w.z*nrm[j*4+2] + w.w*nrm[j*4+3];
        }
        out[(size_t)b*512 + o] = acc;
    }
}

// ---------------------------------------------------------------------------
extern "C" void kernel_launch(void* const* d_in, const int* in_sizes, int n_in,
                              void* d_out, int out_size, void* d_ws, size_t ws_size,
                              hipStream_t stream) {
    const float* x      = (const float*)d_in[0];
    const float* bp     = (const float*)d_in[1];
    const float* w_lin1 = (const float*)d_in[2];
    const float* b_lin1 = (const float*)d_in[3];
    const float* wc1    = (const float*)d_in[4];
    const float* bc1    = (const float*)d_in[5];
    const float* wc2    = (const float*)d_in[6];
    const float* bc2    = (const float*)d_in[7];
    const float* wc3    = (const float*)d_in[8];
    const float* bc3    = (const float*)d_in[9];
    const float* wa1    = (const float*)d_in[10];
    const float* ba1    = (const float*)d_in[11];
    const float* wa2    = (const float*)d_in[12];
    const float* ba2    = (const float*)d_in[13];
    const float* gamma  = (const float*)d_in[14];
    const float* beta   = (const float*)d_in[15];
    const float* wl2    = (const float*)d_in[16];
    const float* bl2    = (const float*)d_in[17];

    float* ws   = (float*)d_ws;
    float* bs   = ws + OFF_BS;
    float* weff = ws + OFF_WEFF;
    unsigned short* w1h = (unsigned short*)(ws + OFF_W1);
    unsigned short* w1l = w1h + 3*128*64;
    unsigned short* w2h = (unsigned short*)(ws + OFF_W2);
    unsigned short* w2l = w2h + 3*128*128;
    unsigned short* w3h = (unsigned short*)(ws + OFF_W3);
    unsigned short* w3l = w3h + 3*128*128;
    float* wa1t = ws + OFF_WA1T;
    float* wa2t = ws + OFF_WA2T;
    float* pm   = ws + OFF_PM;
    float* ps   = ws + OFF_PS;
    float* Ms   = ws + OFF_MS;
    float* Ss   = ws + OFF_SS;
    float* pcm  = ws + OFF_PCM;
    float* pcq  = ws + OFF_PCQ;
    float* h    = ws + OFF_H;    // h, then v
    float* bufA = ws + OFF_A;    // i1, then i3
    float* bufB = ws + OFF_BB;   // s,  then logits

    sort_kernel<<<dim3(1), dim3(64), 0, stream>>>(bp, bs);
    prep_kernel<<<dim3(609), dim3(256), 0, stream>>>(bs, w_lin1, wc1, wc2, wc3, wa1, wa2,
                                                     weff, w1h, w1l, w2h, w2l, w3h, w3l,
                                                     wa1t, wa2t);
    // h = relu(x @ Weff^T + b_lin1)
    gemm_rn<1><<<dim3(R_/128, 1), dim3(256), 0, stream>>>(x, weff, b_lin1, h, R_, NB_, 64);
    // i1 = conv1(h) + b
    dconv_mfma<64, 2, 0><<<dim3(24, B_), dim3(256), 0, stream>>>(h, w1h, w1l, bc1, bufA);
    // s = i1 + i2 = conv2(i1) + b + 2*i1
    dconv_mfma<128, 3, 2><<<dim3(24, B_), dim3(256), 0, stream>>>(bufA, w2h, w2l, bc2, bufB);
    // i3 = conv3(s) + b + s
    dconv_mfma<128, 4, 1><<<dim3(24, B_), dim3(256), 0, stream>>>(bufB, w3h, w3l, bc3, bufA);
    // v = tanh(i3 @ wa1^T + ba1)   (into h buffer)
    gemm_rn<2><<<dim3(R_/128, 1), dim3(256), 0, stream>>>(bufA, wa1t, ba1, h, R_, 128, 64);
    // logits = v @ wa2^T + ba2     (into bufB)
    gemm_rn<0><<<dim3(R_/128, 2), dim3(256), 0, stream>>>(h, wa2t, ba2, bufB, R_, 64, 128);
    // softmax over T + weighted stats
    sm_pass_a<<<dim3(NCH, B_), dim3(128), 0, stream>>>(bufB, pm, ps);
    sm_pass_b<<<dim3(B_), dim3(128), 0, stream>>>(pm, ps, Ms, Ss);
    sm_pass_c<<<dim3(NCH, B_), dim3(128), 0, stream>>>(bufB, bufA, Ms, pcm, pcq);
    final_kernel<<<dim3(B_), dim3(256), 0, stream>>>(pcm, pcq, Ss, gamma, beta, wl2, bl2,
                                                     (float*)d_out);
}

// Round 4
// 655.379 us; speedup vs baseline: 2.0850x; 1.3802x over previous
//
#include <hip/hip_runtime.h>
#include <math.h>

// ---------------------------------------------------------------------------
// ResCNN_ASP_SpeakerEncoder — v3: all GEMMs on MFMA (split-bf16 3-pass);
// asp1+asp2+softmax-pass-a fused into one kernel (v stays in LDS).
// ---------------------------------------------------------------------------

constexpr int B_  = 64;
constexpr int T_  = 3000;
constexpr int NB_ = 257;   // NBINS
constexpr int R_  = B_ * T_;           // 192000 rows
constexpr int NCH = 24;                // softmax T-chunks (24 x 128)
constexpr int CHL = 128;

// workspace layout (float offsets)
constexpr size_t OFF_BS   = 0;                            // sorted binpoints (82)
constexpr size_t OFF_WEFF = 128;                          // ushort hi[64*320]+lo
constexpr size_t OFF_W1   = OFF_WEFF + 20480;             // ushort hi[3*128*64]+lo
constexpr size_t OFF_W2   = OFF_W1  + 3*64*128;           // ushort hi[3*128*128]+lo
constexpr size_t OFF_W3   = OFF_W2  + 3*128*128;
constexpr size_t OFF_WA1  = OFF_W3  + 3*128*128;          // ushort hi[64*128]+lo
constexpr size_t OFF_WA2  = OFF_WA1 + 8192;               // ushort hi[128*64]+lo
constexpr size_t SZ_P     = (size_t)B_*NCH*128;
constexpr size_t OFF_PM   = OFF_WA2 + 8192;
constexpr size_t OFF_PS   = OFF_PM  + SZ_P;
constexpr size_t OFF_MS   = OFF_PS  + SZ_P;               // [B][128]
constexpr size_t OFF_SS   = OFF_MS  + (size_t)B_*128;
constexpr size_t OFF_PCM  = OFF_SS  + (size_t)B_*128;
constexpr size_t OFF_PCQ  = OFF_PCM + SZ_P;
constexpr size_t OFF_H    = OFF_PCQ + SZ_P;               // [R][64]  (h)
constexpr size_t OFF_A    = OFF_H   + (size_t)R_*64;      // [R][128] (i1, later i3)
constexpr size_t OFF_BB   = OFF_A   + (size_t)R_*128;     // [R][128] (s, later logits)

typedef __attribute__((ext_vector_type(8))) short  bf16x8;
typedef __attribute__((ext_vector_type(4))) float  f32x4;
typedef unsigned short ushort_t;

__device__ inline ushort_t f2bf(float f) {                // RNE f32->bf16
    unsigned u = __float_as_uint(f);
    unsigned r = u + 0x7FFFu + ((u >> 16) & 1u);
    return (ushort_t)(r >> 16);
}
__device__ inline float bf2f(ushort_t h) {
    return __uint_as_float(((unsigned)h) << 16);
}

// ---------------------------------------------------------------------------
__global__ void sort_kernel(const float* __restrict__ bp, float* __restrict__ bs) {
    if (threadIdx.x == 0) {
        float tmp[82];
        for (int i = 0; i < 82; ++i) tmp[i] = bp[i];
        for (int i = 1; i < 82; ++i) {
            float key = tmp[i];
            int j = i - 1;
            while (j >= 0 && tmp[j] > key) { tmp[j+1] = tmp[j]; --j; }
            tmp[j+1] = key;
        }
        for (int i = 0; i < 82; ++i) bs[i] = tmp[i];
    }
}

// Builds Weff hi/lo [64][320] (zero-padded K), conv weights bf16 hi/lo
// [k][c][ci], and asp weights bf16 hi/lo (elementwise, [o][ci] layout kept).
__global__ void prep_kernel(const float* __restrict__ bs, const float* __restrict__ wl1,
                            const float* __restrict__ wc1, const float* __restrict__ wc2,
                            const float* __restrict__ wc3, const float* __restrict__ wa1,
                            const float* __restrict__ wa2,
                            ushort_t* __restrict__ weh, ushort_t* __restrict__ wel,
                            ushort_t* __restrict__ w1h, ushort_t* __restrict__ w1l,
                            ushort_t* __restrict__ w2h, ushort_t* __restrict__ w2l,
                            ushort_t* __restrict__ w3h, ushort_t* __restrict__ w3l,
                            ushort_t* __restrict__ wa1h, ushort_t* __restrict__ wa1l,
                            ushort_t* __restrict__ wa2h, ushort_t* __restrict__ wa2l) {
    int gid = blockIdx.x * 256 + threadIdx.x;
    if (gid < 64*320) {                            // Weff[o][f], f padded to 320
        int o = gid / 320, f = gid % 320;
        float acc = 0.0f;
        if (f == 0) acc = wl1[o*80];               // filt[:,:,0] = x[:,:,0]
        else if (f < NB_) {
            for (int n = 1; n < 79; ++n) {         // fb rows 1..78 (row 79 zero)
                float bn = bs[n], bn1 = bs[n+1], bn2 = bs[n+2];
                int ibn  = (int)floorf(bn);
                int ibn1 = (int)floorf(bn1);
                int ibn2 = (int)floorf(bn2);
                float fbv = 0.0f;
                if (f >= ibn && f < ibn1) {
                    float d = (bn1-bn)*(bn1-bn);
                    fbv = ((float)f - bn) / (d > 0.0f ? d : 1.0f);
                } else if (f >= ibn1 && f < ibn2) {
                    float d = (bn2-bn1)*(bn2-bn1);
                    fbv = (bn2 - (float)f) / (d > 0.0f ? d : 1.0f);
                }
                acc += wl1[o*80 + n] * fbv;
            }
        }
        ushort_t h = f2bf(acc);
        weh[gid] = h; wel[gid] = f2bf(acc - bf2f(h));
        return;
    }
    gid -= 64*320;
    if (gid < 3*128*64) {                          // conv1: [k][c][ci=64]
        int k = gid / (128*64), rem = gid % (128*64);
        int c = rem >> 6, ci = rem & 63;
        float v = wc1[(c*64 + ci)*3 + k];
        ushort_t h = f2bf(v);
        w1h[gid] = h; w1l[gid] = f2bf(v - bf2f(h));
        return;
    }
    gid -= 3*128*64;
    if (gid < 3*128*128) {                         // conv2: [k][c][ci=128]
        int k = gid / (128*128), rem = gid % (128*128);
        int c = rem >> 7, ci = rem & 127;
        float v = wc2[(c*128 + ci)*3 + k];
        ushort_t h = f2bf(v);
        w2h[gid] = h; w2l[gid] = f2bf(v - bf2f(h));
        return;
    }
    gid -= 3*128*128;
    if (gid < 3*128*128) {                         // conv3
        int k = gid / (128*128), rem = gid % (128*128);
        int c = rem >> 7, ci = rem & 127;
        float v = wc3[(c*128 + ci)*3 + k];
        ushort_t h = f2bf(v);
        w3h[gid] = h; w3l[gid] = f2bf(v - bf2f(h));
        return;
    }
    gid -= 3*128*128;
    if (gid < 64*128) {                            // wa1 [o=64][ci=128] elementwise
        float v = wa1[gid];
        ushort_t h = f2bf(v);
        wa1h[gid] = h; wa1l[gid] = f2bf(v - bf2f(h));
        return;
    }
    gid -= 64*128;
    if (gid < 128*64) {                            // wa2 [o=128][ci=64] elementwise
        float v = wa2[gid];
        ushort_t h = f2bf(v);
        wa2h[gid] = h; wa2l[gid] = f2bf(v - bf2f(h));
        return;
    }
}

// ---------------------------------------------------------------------------
// lin1: h[t][c] = relu( sum_k x[t][k] * Weff[c][k] + b[c] ), K=257 (pad 320).
// Split-bf16 MFMA, tile 128t x 64c, 4 waves (2x2). x rows stride 257 (odd) ->
// staged via 4-dword loads + packed ds_write_b64.
__launch_bounds__(256)
__global__ void lin1_mfma(const float* __restrict__ X,
                          const ushort_t* __restrict__ Wh, const ushort_t* __restrict__ Wl,
                          const float* __restrict__ bias, float* __restrict__ H) {
    __shared__ __align__(16) ushort_t ash[128*64];
    __shared__ __align__(16) ushort_t asl[128*64];
    const int tid  = threadIdx.x;
    const int lane = tid & 63;
    const int wid  = tid >> 6;
    const int wy   = wid >> 1, wx = wid & 1;
    const int l16  = lane & 15, l4 = lane >> 4;
    const int r0   = blockIdx.x * 128;

    f32x4 acc[4][2];
    const f32x4 z = {0.f,0.f,0.f,0.f};
#pragma unroll
    for (int m = 0; m < 4; ++m) { acc[m][0] = z; acc[m][1] = z; }

    for (int k0 = 0; k0 < NB_; k0 += 64) {
        const int krem = NB_ - k0;                 // 64,64,64,64,1
        __syncthreads();
        for (int q = tid; q < 2048; q += 256) {
            int r = q >> 4, qq = (q & 15) << 2;
            const float* src = X + (size_t)(r0 + r)*NB_ + k0 + qq;
            float v0 = (qq     < krem) ? src[0] : 0.f;
            float v1 = (qq + 1 < krem) ? src[1] : 0.f;
            float v2 = (qq + 2 < krem) ? src[2] : 0.f;
            float v3 = (qq + 3 < krem) ? src[3] : 0.f;
            ushort_t h0 = f2bf(v0), h1 = f2bf(v1), h2 = f2bf(v2), h3 = f2bf(v3);
            ushort_t g0 = f2bf(v0 - bf2f(h0)), g1 = f2bf(v1 - bf2f(h1));
            ushort_t g2 = f2bf(v2 - bf2f(h2)), g3 = f2bf(v3 - bf2f(h3));
            unsigned byte = ((unsigned)(r*64 + qq))*2u ^ ((unsigned)((r & 7) << 4));
            uint2 ph; ph.x = (unsigned)h0 | ((unsigned)h1 << 16); ph.y = (unsigned)h2 | ((unsigned)h3 << 16);
            uint2 pl; pl.x = (unsigned)g0 | ((unsigned)g1 << 16); pl.y = (unsigned)g2 | ((unsigned)g3 << 16);
            *(uint2*)((char*)ash + byte) = ph;
            *(uint2*)((char*)asl + byte) = pl;
        }
        __syncthreads();
#pragma unroll
        for (int kk = 0; kk < 64; kk += 32) {
            bf16x8 bh[2], bl[2];
#pragma unroll
            for (int n = 0; n < 2; ++n) {
                int c = wx*32 + n*16 + l16;
                size_t off = (size_t)c*320 + k0 + kk + l4*8;
                bh[n] = *(const bf16x8*)(Wh + off);
                bl[n] = *(const bf16x8*)(Wl + off);
            }
            bf16x8 fh[4], fl[4];
#pragma unroll
            for (int m = 0; m < 4; ++m) {
                int r = wy*64 + m*16 + l16;
                unsigned byte = ((unsigned)(r*64 + kk + l4*8))*2u ^ ((unsigned)((r & 7) << 4));
                fh[m] = *(const bf16x8*)((const char*)ash + byte);
                fl[m] = *(const bf16x8*)((const char*)asl + byte);
            }
#pragma unroll
            for (int m = 0; m < 4; ++m)
#pragma unroll
                for (int n = 0; n < 2; ++n) {
                    acc[m][n] = __builtin_amdgcn_mfma_f32_16x16x32_bf16(fh[m], bh[n], acc[m][n], 0, 0, 0);
                    acc[m][n] = __builtin_amdgcn_mfma_f32_16x16x32_bf16(fh[m], bl[n], acc[m][n], 0, 0, 0);
                    acc[m][n] = __builtin_amdgcn_mfma_f32_16x16x32_bf16(fl[m], bh[n], acc[m][n], 0, 0, 0);
                }
        }
    }
#pragma unroll
    for (int m = 0; m < 4; ++m)
#pragma unroll
        for (int n = 0; n < 2; ++n) {
            int c = wx*32 + n*16 + l16;
            float bv = bias[c];
            int rb = r0 + wy*64 + m*16 + l4*4;
#pragma unroll
            for (int rg = 0; rg < 4; ++rg)
                H[(size_t)(rb + rg)*64 + c] = fmaxf(acc[m][n][rg] + bv, 0.0f);
        }
}

// ---------------------------------------------------------------------------
// Dilated conv (K=3) via split-bf16 MFMA (unchanged from v2).
template<int CIN, int DIL, int RES>
__launch_bounds__(256)
__global__ void dconv_mfma(const float* __restrict__ X,
                           const ushort_t* __restrict__ Wh,
                           const ushort_t* __restrict__ Wl,
                           const float* __restrict__ bias, float* __restrict__ Y) {
    constexpr int TT = 128;
    constexpr int HS = TT + 2*DIL;
    __shared__ __align__(16) ushort_t hsh[HS*CIN];
    __shared__ __align__(16) ushort_t hsl[HS*CIN];

    const int tid  = threadIdx.x;
    const int lane = tid & 63;
    const int wid  = tid >> 6;
    const int wy   = wid >> 1;
    const int wx   = wid & 1;
    const int l16  = lane & 15;
    const int l4   = lane >> 4;
    const int t0   = blockIdx.x * TT;
    const int b    = blockIdx.y;

    for (int idx = tid; idx < HS*CIN/4; idx += 256) {
        int e  = idx << 2;
        int r  = e / CIN, ci = e % CIN;
        int t  = t0 - DIL + r;
        float4 v = make_float4(0.f, 0.f, 0.f, 0.f);
        if (t >= 0 && t < T_) v = *(const float4*)&X[((size_t)b*T_ + t)*CIN + ci];
        ushort_t h0 = f2bf(v.x), h1 = f2bf(v.y), h2 = f2bf(v.z), h3 = f2bf(v.w);
        ushort_t g0 = f2bf(v.x - bf2f(h0)), g1 = f2bf(v.y - bf2f(h1));
        ushort_t g2 = f2bf(v.z - bf2f(h2)), g3 = f2bf(v.w - bf2f(h3));
        unsigned byte = ((unsigned)(r*CIN + ci))*2u ^ ((unsigned)((r & 7) << 4));
        uint2 ph; ph.x = (unsigned)h0 | ((unsigned)h1 << 16); ph.y = (unsigned)h2 | ((unsigned)h3 << 16);
        uint2 pl; pl.x = (unsigned)g0 | ((unsigned)g1 << 16); pl.y = (unsigned)g2 | ((unsigned)g3 << 16);
        *(uint2*)((char*)hsh + byte) = ph;
        *(uint2*)((char*)hsl + byte) = pl;
    }
    __syncthreads();

    f32x4 acc[4][4];
    const f32x4 z = {0.f, 0.f, 0.f, 0.f};
#pragma unroll
    for (int m = 0; m < 4; ++m)
#pragma unroll
        for (int n = 0; n < 4; ++n) acc[m][n] = z;

    for (int k = 0; k < 3; ++k) {
#pragma unroll
        for (int cib = 0; cib < CIN; cib += 32) {
            bf16x8 bh[4], bl[4];
#pragma unroll
            for (int n = 0; n < 4; ++n) {
                int c = wx*64 + n*16 + l16;
                size_t off = ((size_t)(k*128 + c))*CIN + cib + l4*8;
                bh[n] = *(const bf16x8*)(Wh + off);
                bl[n] = *(const bf16x8*)(Wl + off);
            }
            bf16x8 ah[4], al[4];
#pragma unroll
            for (int m = 0; m < 4; ++m) {
                int r = wy*64 + m*16 + l16 + k*DIL;
                unsigned byte = ((unsigned)(r*CIN + cib + l4*8))*2u
                              ^ ((unsigned)((r & 7) << 4));
                ah[m] = *(const bf16x8*)((const char*)hsh + byte);
                al[m] = *(const bf16x8*)((const char*)hsl + byte);
            }
#pragma unroll
            for (int m = 0; m < 4; ++m)
#pragma unroll
                for (int n = 0; n < 4; ++n) {
                    acc[m][n] = __builtin_amdgcn_mfma_f32_16x16x32_bf16(ah[m], bh[n], acc[m][n], 0, 0, 0);
                    acc[m][n] = __builtin_amdgcn_mfma_f32_16x16x32_bf16(ah[m], bl[n], acc[m][n], 0, 0, 0);
                    acc[m][n] = __builtin_amdgcn_mfma_f32_16x16x32_bf16(al[m], bh[n], acc[m][n], 0, 0, 0);
                }
        }
    }

#pragma unroll
    for (int m = 0; m < 4; ++m) {
        int tl_base = wy*64 + m*16 + l4*4;
#pragma unroll
        for (int n = 0; n < 4; ++n) {
            int c = wx*64 + n*16 + l16;
            float bv = bias[c];
#pragma unroll
            for (int rg = 0; rg < 4; ++rg) {
                int tl = tl_base + rg;
                int t  = t0 + tl;
                if (t < T_) {
                    float v = acc[m][n][rg] + bv;
                    if (RES >= 1) {
                        int r = tl + DIL;
                        unsigned byte = ((unsigned)(r*CIN + c))*2u
                                      ^ ((unsigned)((r & 7) << 4));
                        float cen = bf2f(*(const ushort_t*)((const char*)hsh + byte))
                                  + bf2f(*(const ushort_t*)((const char*)hsl + byte));
                        v += (RES == 2) ? 2.0f*cen : cen;
                    }
                    Y[((size_t)b*T_ + t)*128 + c] = v;
                }
            }
        }
    }
}

// ---------------------------------------------------------------------------
// Fused ASP: v = tanh(i3 @ wa1^T + ba1); logits = v @ wa2^T + ba2 (stored);
// plus per-(b,chunk,c) online softmax partials (max, sumexp) over t.
// Tile: 128 t (one chunk) x one batch. v lives only in LDS (bf16 hi/lo).
__launch_bounds__(256)
__global__ void asp_fused(const float* __restrict__ I3,
                          const ushort_t* __restrict__ Wa1h, const ushort_t* __restrict__ Wa1l,
                          const ushort_t* __restrict__ Wa2h, const ushort_t* __restrict__ Wa2l,
                          const float* __restrict__ ba1, const float* __restrict__ ba2,
                          float* __restrict__ logits,
                          float* __restrict__ pm, float* __restrict__ ps) {
    __shared__ __align__(16) ushort_t ah_[128*64];
    __shared__ __align__(16) ushort_t al_[128*64];
    __shared__ __align__(16) ushort_t vh_[128*64];
    __shared__ __align__(16) ushort_t vl_[128*64];
    __shared__ float redM[2][128];
    __shared__ float redS[2][128];

    const int tid  = threadIdx.x;
    const int lane = tid & 63;
    const int wid  = tid >> 6;
    const int wy   = wid >> 1, wx = wid & 1;
    const int l16  = lane & 15, l4 = lane >> 4;
    const int ch   = blockIdx.x;
    const int b    = blockIdx.y;
    const int t0   = ch * CHL;                     // global t of tile row 0

    // ---- stage 1: v = tanh(i3 @ wa1^T + ba1), K=128 in 2 chunks ----
    f32x4 acc1[4][2];
    const f32x4 z = {0.f,0.f,0.f,0.f};
#pragma unroll
    for (int m = 0; m < 4; ++m) { acc1[m][0] = z; acc1[m][1] = z; }

    for (int k0 = 0; k0 < 128; k0 += 64) {
        __syncthreads();
        for (int q = tid; q < 2048; q += 256) {
            int r = q >> 4, qq = (q & 15) << 2;
            int t = t0 + r;
            float4 v = make_float4(0.f,0.f,0.f,0.f);
            if (t < T_) v = *(const float4*)&I3[((size_t)b*T_ + t)*128 + k0 + qq];
            ushort_t h0 = f2bf(v.x), h1 = f2bf(v.y), h2 = f2bf(v.z), h3 = f2bf(v.w);
            ushort_t g0 = f2bf(v.x - bf2f(h0)), g1 = f2bf(v.y - bf2f(h1));
            ushort_t g2 = f2bf(v.z - bf2f(h2)), g3 = f2bf(v.w - bf2f(h3));
            unsigned byte = ((unsigned)(r*64 + qq))*2u ^ ((unsigned)((r & 7) << 4));
            uint2 ph; ph.x = (unsigned)h0 | ((unsigned)h1 << 16); ph.y = (unsigned)h2 | ((unsigned)h3 << 16);
            uint2 pl; pl.x = (unsigned)g0 | ((unsigned)g1 << 16); pl.y = (unsigned)g2 | ((unsigned)g3 << 16);
            *(uint2*)((char*)ah_ + byte) = ph;
            *(uint2*)((char*)al_ + byte) = pl;
        }
        __syncthreads();
#pragma unroll
        for (int kk = 0; kk < 64; kk += 32) {
            bf16x8 bh[2], bl[2];
#pragma unroll
            for (int n = 0; n < 2; ++n) {
                int c = wx*32 + n*16 + l16;
                size_t off = (size_t)c*128 + k0 + kk + l4*8;
                bh[n] = *(const bf16x8*)(Wa1h + off);
                bl[n] = *(const bf16x8*)(Wa1l + off);
            }
            bf16x8 fh[4], fl[4];
#pragma unroll
            for (int m = 0; m < 4; ++m) {
                int r = wy*64 + m*16 + l16;
                unsigned byte = ((unsigned)(r*64 + kk + l4*8))*2u ^ ((unsigned)((r & 7) << 4));
                fh[m] = *(const bf16x8*)((const char*)ah_ + byte);
                fl[m] = *(const bf16x8*)((const char*)al_ + byte);
            }
#pragma unroll
            for (int m = 0; m < 4; ++m)
#pragma unroll
                for (int n = 0; n < 2; ++n) {
                    acc1[m][n] = __builtin_amdgcn_mfma_f32_16x16x32_bf16(fh[m], bh[n], acc1[m][n], 0, 0, 0);
                    acc1[m][n] = __builtin_amdgcn_mfma_f32_16x16x32_bf16(fh[m], bl[n], acc1[m][n], 0, 0, 0);
                    acc1[m][n] = __builtin_amdgcn_mfma_f32_16x16x32_bf16(fl[m], bh[n], acc1[m][n], 0, 0, 0);
                }
        }
    }
    // epilogue 1: tanh, write v (t x 64) to LDS bf16 hi/lo
#pragma unroll
    for (int m = 0; m < 4; ++m)
#pragma unroll
        for (int n = 0; n < 2; ++n) {
            int c = wx*32 + n*16 + l16;
            float bv = ba1[c];
            int rb = wy*64 + m*16 + l4*4;
#pragma unroll
            for (int rg = 0; rg < 4; ++rg) {
                float v = tanhf(acc1[m][n][rg] + bv);
                int r = rb + rg;
                unsigned byte = ((unsigned)(r*64 + c))*2u ^ ((unsigned)((r & 7) << 4));
                ushort_t h = f2bf(v);
                *(ushort_t*)((char*)vh_ + byte) = h;
                *(ushort_t*)((char*)vl_ + byte) = f2bf(v - bf2f(h));
            }
        }
    __syncthreads();

    // ---- stage 2: D[n][t] = sum_k wa2[n][k] v[t][k] + ba2[n] ----
    f32x4 acc2[4][4];
#pragma unroll
    for (int m = 0; m < 4; ++m)
#pragma unroll
        for (int j = 0; j < 4; ++j) acc2[m][j] = z;

#pragma unroll
    for (int kk = 0; kk < 64; kk += 32) {
        bf16x8 awh[4], awl[4];
#pragma unroll
        for (int m = 0; m < 4; ++m) {
            int n = wy*64 + m*16 + l16;
            size_t off = (size_t)n*64 + kk + l4*8;
            awh[m] = *(const bf16x8*)(Wa2h + off);
            awl[m] = *(const bf16x8*)(Wa2l + off);
        }
        bf16x8 bvh[4], bvl[4];
#pragma unroll
        for (int j = 0; j < 4; ++j) {
            int r = wx*64 + j*16 + l16;
            unsigned byte = ((unsigned)(r*64 + kk + l4*8))*2u ^ ((unsigned)((r & 7) << 4));
            bvh[j] = *(const bf16x8*)((const char*)vh_ + byte);
            bvl[j] = *(const bf16x8*)((const char*)vl_ + byte);
        }
#pragma unroll
        for (int m = 0; m < 4; ++m)
#pragma unroll
            for (int j = 0; j < 4; ++j) {
                acc2[m][j] = __builtin_amdgcn_mfma_f32_16x16x32_bf16(awh[m], bvh[j], acc2[m][j], 0, 0, 0);
                acc2[m][j] = __builtin_amdgcn_mfma_f32_16x16x32_bf16(awh[m], bvl[j], acc2[m][j], 0, 0, 0);
                acc2[m][j] = __builtin_amdgcn_mfma_f32_16x16x32_bf16(awl[m], bvh[j], acc2[m][j], 0, 0, 0);
            }
    }

    // epilogue 2: bias add, store logits (t-major), softmax partials over t
#pragma unroll
    for (int m = 0; m < 4; ++m) {
        const float4 bv = *(const float4*)&ba2[wy*64 + m*16 + l4*4];
#pragma unroll
        for (int j = 0; j < 4; ++j) {
            acc2[m][j][0] += bv.x; acc2[m][j][1] += bv.y;
            acc2[m][j][2] += bv.z; acc2[m][j][3] += bv.w;
        }
    }
#pragma unroll
    for (int j = 0; j < 4; ++j) {
        int tg = t0 + wx*64 + j*16 + l16;
        if (tg < T_) {
#pragma unroll
            for (int m = 0; m < 4; ++m) {
                float4 o = make_float4(acc2[m][j][0], acc2[m][j][1], acc2[m][j][2], acc2[m][j][3]);
                *(float4*)&logits[((size_t)b*T_ + tg)*128 + wy*64 + m*16 + l4*4] = o;
            }
        }
    }
    // per-n reduce over t: within-thread (4 j) then shfl over l16 bits
#pragma unroll
    for (int m = 0; m < 4; ++m)
#pragma unroll
        for (int rg = 0; rg < 4; ++rg) {
            int n = wy*64 + m*16 + l4*4 + rg;
            float mx = -INFINITY;
#pragma unroll
            for (int j = 0; j < 4; ++j) {
                int tg = t0 + wx*64 + j*16 + l16;
                if (tg < T_) mx = fmaxf(mx, acc2[m][j][rg]);
            }
            mx = fmaxf(mx, __shfl_xor(mx, 1));
            mx = fmaxf(mx, __shfl_xor(mx, 2));
            mx = fmaxf(mx, __shfl_xor(mx, 4));
            mx = fmaxf(mx, __shfl_xor(mx, 8));
            float se = 0.0f;
#pragma unroll
            for (int j = 0; j < 4; ++j) {
                int tg = t0 + wx*64 + j*16 + l16;
                if (tg < T_) se += expf(acc2[m][j][rg] - mx);
            }
            se += __shfl_xor(se, 1);
            se += __shfl_xor(se, 2);
            se += __shfl_xor(se, 4);
            se += __shfl_xor(se, 8);
            if (l16 == 0) { redM[wx][n] = mx; redS[wx][n] = se; }
        }
    __syncthreads();
    if (tid < 128) {
        float m0 = redM[0][tid], m1 = redM[1][tid];
        float M  = fmaxf(m0, m1);
        float S  = 0.0f;
        if (m0 > -INFINITY) S += redS[0][tid] * expf(m0 - M);
        if (m1 > -INFINITY) S += redS[1][tid] * expf(m1 - M);
        pm[((size_t)b*NCH + ch)*128 + tid] = M;
        ps[((size_t)b*NCH + ch)*128 + tid] = S;
    }
}

// ---------------------------------------------------------------------------
__global__ void sm_pass_b(const float* __restrict__ pm, const float* __restrict__ ps,
                          float* __restrict__ Ms, float* __restrict__ Ss) {
    const int c = threadIdx.x, b = blockIdx.x;
    float M = -INFINITY;
    for (int ch = 0; ch < NCH; ++ch) M = fmaxf(M, pm[((size_t)b*NCH + ch)*128 + c]);
    float S = 0.0f;
    for (int ch = 0; ch < NCH; ++ch) {
        float m = pm[((size_t)b*NCH + ch)*128 + c];
        if (m > -INFINITY) S += ps[((size_t)b*NCH + ch)*128 + c] * expf(m - M);
    }
    Ms[b*128 + c] = M;
    Ss[b*128 + c] = S;
}

__global__ void sm_pass_c(const float* __restrict__ a, const float* __restrict__ i3,
                          const float* __restrict__ Ms, float* __restrict__ pcm,
                          float* __restrict__ pcq) {
    const int c = threadIdx.x, ch = blockIdx.x, b = blockIdx.y;
    const int ts = ch * CHL, te = min(T_, ts + CHL);
    const float M = Ms[b*128 + c];
    float am = 0.0f, aq = 0.0f;
    for (int t = ts; t < te; ++t) {
        float p = expf(a[((size_t)b*T_ + t)*128 + c] - M);
        float x = i3[((size_t)b*T_ + t)*128 + c];
        am += p*x;
        aq += p*x*x;
    }
    pcm[((size_t)b*NCH + ch)*128 + c] = am;
    pcq[((size_t)b*NCH + ch)*128 + c] = aq;
}

// stats -> layernorm(256) -> linear 256->512
__global__ void final_kernel(const float* __restrict__ pcm, const float* __restrict__ pcq,
                             const float* __restrict__ Ss, const float* __restrict__ gamma,
                             const float* __restrict__ beta, const float* __restrict__ w2,
                             const float* __restrict__ b2, float* __restrict__ out) {
    __shared__ float row[256];
    __shared__ float nrm[256];
    __shared__ float red[8];
    const int tid = threadIdx.x, b = blockIdx.x;
    if (tid < 128) {
        float sm = 0.0f, sq = 0.0f;
        for (int ch = 0; ch < NCH; ++ch) {
            sm += pcm[((size_t)b*NCH + ch)*128 + tid];
            sq += pcq[((size_t)b*NCH + ch)*128 + tid];
        }
        float S = Ss[b*128 + tid];
        float mean = sm / S;
        float q    = sq / S;
        float resid = q - mean*mean;
        float stdv  = sqrtf(fmaxf(resid, 1e-9f));
        row[tid]       = mean;
        row[128 + tid] = stdv;
    }
    __syncthreads();
    float v  = row[tid];
    float s1 = v, s2 = v*v;
    for (int off = 32; off >= 1; off >>= 1) {
        s1 += __shfl_down(s1, off, 64);
        s2 += __shfl_down(s2, off, 64);
    }
    if ((tid & 63) == 0) { red[tid >> 6] = s1; red[4 + (tid >> 6)] = s2; }
    __syncthreads();
    float S1 = red[0] + red[1] + red[2] + red[3];
    float S2 = red[4] + red[5] + red[6] + red[7];
    float mu  = S1 / 256.0f;
    float var = S2 / 256.0f - mu*mu;
    float inv = 1.0f / sqrtf(var + 1e-5f);
    nrm[tid] = (v - mu)*inv*gamma[tid] + beta[tid];
    __syncthreads();
#pragma unroll
    for (int oo = 0; oo < 2; ++oo) {
        int o = tid + oo*256;
        float acc = b2[o];
        const float4* wr = (const float4*)&w2[(size_t)o*256];
        for (int j = 0; j < 64; ++j) {
            float4 w = wr[j];
            acc += w.x*nrm[j*4] + w.y*nrm[j*4+1] + w.z*nrm[j*4+2] + w.w*nrm[j*4+3];
        }
        out[(size_t)b*512 + o] = acc;
    }
}

// ---------------------------------------------------------------------------
extern "C" void kernel_launch(void* const* d_in, const int* in_sizes, int n_in,
                              void* d_out, int out_size, void* d_ws, size_t ws_size,
                              hipStream_t stream) {
    const float* x      = (const float*)d_in[0];
    const float* bp     = (const float*)d_in[1];
    const float* w_lin1 = (const float*)d_in[2];
    const float* b_lin1 = (const float*)d_in[3];
    const float* wc1    = (const float*)d_in[4];
    const float* bc1    = (const float*)d_in[5];
    const float* wc2    = (const float*)d_in[6];
    const float* bc2    = (const float*)d_in[7];
    const float* wc3    = (const float*)d_in[8];
    const float* bc3    = (const float*)d_in[9];
    const float* wa1    = (const float*)d_in[10];
    const float* ba1    = (const float*)d_in[11];
    const float* wa2    = (const float*)d_in[12];
    const float* ba2    = (const float*)d_in[13];
    const float* gamma  = (const float*)d_in[14];
    const float* beta   = (const float*)d_in[15];
    const float* wl2    = (const float*)d_in[16];
    const float* bl2    = (const float*)d_in[17];

    float* ws   = (float*)d_ws;
    float* bs   = ws + OFF_BS;
    ushort_t* weh  = (ushort_t*)(ws + OFF_WEFF);
    ushort_t* wel  = weh + 64*320;
    ushort_t* w1h  = (ushort_t*)(ws + OFF_W1);
    ushort_t* w1l  = w1h + 3*128*64;
    ushort_t* w2h  = (ushort_t*)(ws + OFF_W2);
    ushort_t* w2l  = w2h + 3*128*128;
    ushort_t* w3h  = (ushort_t*)(ws + OFF_W3);
    ushort_t* w3l  = w3h + 3*128*128;
    ushort_t* wa1h = (ushort_t*)(ws + OFF_WA1);
    ushort_t* wa1l = wa1h + 64*128;
    ushort_t* wa2h = (ushort_t*)(ws + OFF_WA2);
    ushort_t* wa2l = wa2h + 128*64;
    float* pm   = ws + OFF_PM;
    float* ps   = ws + OFF_PS;
    float* Ms   = ws + OFF_MS;
    float* Ss   = ws + OFF_SS;
    float* pcm  = ws + OFF_PCM;
    float* pcq  = ws + OFF_PCQ;
    float* h    = ws + OFF_H;
    float* bufA = ws + OFF_A;    // i1, then i3
    float* bufB = ws + OFF_BB;   // s,  then logits

    sort_kernel<<<dim3(1), dim3(64), 0, stream>>>(bp, bs);
    prep_kernel<<<dim3(624), dim3(256), 0, stream>>>(bs, w_lin1, wc1, wc2, wc3, wa1, wa2,
                                                     weh, wel, w1h, w1l, w2h, w2l, w3h, w3l,
                                                     wa1h, wa1l, wa2h, wa2l);
    // h = relu(x @ Weff^T + b_lin1)
    lin1_mfma<<<dim3(R_/128), dim3(256), 0, stream>>>(x, weh, wel, b_lin1, h);
    // i1 = conv1(h) + b
    dconv_mfma<64, 2, 0><<<dim3(24, B_), dim3(256), 0, stream>>>(h, w1h, w1l, bc1, bufA);
    // s = i1 + i2 = conv2(i1) + b + 2*i1
    dconv_mfma<128, 3, 2><<<dim3(24, B_), dim3(256), 0, stream>>>(bufA, w2h, w2l, bc2, bufB);
    // i3 = conv3(s) + b + s
    dconv_mfma<128, 4, 1><<<dim3(24, B_), dim3(256), 0, stream>>>(bufB, w3h, w3l, bc3, bufA);
    // fused asp1+asp2+softmax partials (logits into bufB)
    asp_fused<<<dim3(NCH, B_), dim3(256), 0, stream>>>(bufA, wa1h, wa1l, wa2h, wa2l,
                                                       ba1, ba2, bufB, pm, ps);
    sm_pass_b<<<dim3(B_), dim3(128), 0, stream>>>(pm, ps, Ms, Ss);
    sm_pass_c<<<dim3(NCH, B_), dim3(128), 0, stream>>>(bufB, bufA, Ms, pcm, pcq);
    final_kernel<<<dim3(B_), dim3(256), 0, stream>>>(pcm, pcq, Ss, gamma, beta, wl2, bl2,
                                                     (float*)d_out);
}

// Round 5
// 579.837 us; speedup vs baseline: 2.3566x; 1.1303x over previous
//
#include <hip/hip_runtime.h>
#include <math.h>

// ---------------------------------------------------------------------------
// ResCNN_ASP_SpeakerEncoder — v4: lin1 pipelined (reg-prefetch, K-tail as
// rank-1 fp32 epilogue), cvt_pk bf16 split everywhere, vectorized sm_pass_c.
// ---------------------------------------------------------------------------

constexpr int B_  = 64;
constexpr int T_  = 3000;
constexpr int NB_ = 257;   // NBINS
constexpr int R_  = B_ * T_;           // 192000 rows
constexpr int NCH = 24;                // softmax T-chunks (24 x 128)
constexpr int CHL = 128;

// workspace layout (float offsets)
constexpr size_t OFF_BS    = 0;                            // sorted binpoints (82)
constexpr size_t OFF_WEFF  = 128;                          // ushort hi[64*320]+lo
constexpr size_t OFF_WTAIL = OFF_WEFF + 20480;             // fp32 [64]
constexpr size_t OFF_W1    = OFF_WTAIL + 128;              // ushort hi[3*128*64]+lo
constexpr size_t OFF_W2    = OFF_W1  + 3*64*128;           // ushort hi[3*128*128]+lo
constexpr size_t OFF_W3    = OFF_W2  + 3*128*128;
constexpr size_t OFF_WA1   = OFF_W3  + 3*128*128;          // ushort hi[64*128]+lo
constexpr size_t OFF_WA2   = OFF_WA1 + 8192;               // ushort hi[128*64]+lo
constexpr size_t SZ_P      = (size_t)B_*NCH*128;
constexpr size_t OFF_PM    = OFF_WA2 + 8192;
constexpr size_t OFF_PS    = OFF_PM  + SZ_P;
constexpr size_t OFF_MS    = OFF_PS  + SZ_P;               // [B][128]
constexpr size_t OFF_SS    = OFF_MS  + (size_t)B_*128;
constexpr size_t OFF_PCM   = OFF_SS  + (size_t)B_*128;
constexpr size_t OFF_PCQ   = OFF_PCM + SZ_P;
constexpr size_t OFF_H     = OFF_PCQ + SZ_P;               // [R][64]  (h)
constexpr size_t OFF_A     = OFF_H   + (size_t)R_*64;      // [R][128] (i1, later i3)
constexpr size_t OFF_BB    = OFF_A   + (size_t)R_*128;     // [R][128] (s, later logits)

typedef __attribute__((ext_vector_type(8))) short  bf16x8;
typedef __attribute__((ext_vector_type(4))) float  f32x4;
typedef __attribute__((ext_vector_type(4), aligned(4))) float float4a;  // 4B-aligned ok
typedef unsigned short ushort_t;

__device__ inline ushort_t f2bf(float f) {                // RNE f32->bf16
    unsigned u = __float_as_uint(f);
    unsigned r = u + 0x7FFFu + ((u >> 16) & 1u);
    return (ushort_t)(r >> 16);
}
__device__ inline float bf2f(ushort_t h) {
    return __uint_as_float(((unsigned)h) << 16);
}

// hw-packed split: v -> bf16 hi pair + bf16 lo pair (RNE), 6 insts per 4 elems
__device__ inline void split_pack(float x, float y, float z, float w,
                                  uint2 &ph, uint2 &pl) {
    unsigned hx, hy;
    asm("v_cvt_pk_bf16_f32 %0, %1, %2" : "=v"(hx) : "v"(x), "v"(y));
    asm("v_cvt_pk_bf16_f32 %0, %1, %2" : "=v"(hy) : "v"(z), "v"(w));
    float l0 = x - __uint_as_float(hx << 16);
    float l1 = y - __uint_as_float(hx & 0xFFFF0000u);
    float l2 = z - __uint_as_float(hy << 16);
    float l3 = w - __uint_as_float(hy & 0xFFFF0000u);
    unsigned lx, ly;
    asm("v_cvt_pk_bf16_f32 %0, %1, %2" : "=v"(lx) : "v"(l0), "v"(l1));
    asm("v_cvt_pk_bf16_f32 %0, %1, %2" : "=v"(ly) : "v"(l2), "v"(l3));
    ph.x = hx; ph.y = hy; pl.x = lx; pl.y = ly;
}

// ---------------------------------------------------------------------------
__global__ void sort_kernel(const float* __restrict__ bp, float* __restrict__ bs) {
    if (threadIdx.x == 0) {
        float tmp[82];
        for (int i = 0; i < 82; ++i) tmp[i] = bp[i];
        for (int i = 1; i < 82; ++i) {
            float key = tmp[i];
            int j = i - 1;
            while (j >= 0 && tmp[j] > key) { tmp[j+1] = tmp[j]; --j; }
            tmp[j+1] = key;
        }
        for (int i = 0; i < 82; ++i) bs[i] = tmp[i];
    }
}

// Builds Weff hi/lo [64][320] (zero-padded K) + fp32 tail col 256, conv
// weights bf16 hi/lo [k][c][ci], asp weights bf16 hi/lo elementwise.
__global__ void prep_kernel(const float* __restrict__ bs, const float* __restrict__ wl1,
                            const float* __restrict__ wc1, const float* __restrict__ wc2,
                            const float* __restrict__ wc3, const float* __restrict__ wa1,
                            const float* __restrict__ wa2,
                            ushort_t* __restrict__ weh, ushort_t* __restrict__ wel,
                            float* __restrict__ wtail,
                            ushort_t* __restrict__ w1h, ushort_t* __restrict__ w1l,
                            ushort_t* __restrict__ w2h, ushort_t* __restrict__ w2l,
                            ushort_t* __restrict__ w3h, ushort_t* __restrict__ w3l,
                            ushort_t* __restrict__ wa1h, ushort_t* __restrict__ wa1l,
                            ushort_t* __restrict__ wa2h, ushort_t* __restrict__ wa2l) {
    int gid = blockIdx.x * 256 + threadIdx.x;
    if (gid < 64*320) {                            // Weff[o][f], f padded to 320
        int o = gid / 320, f = gid % 320;
        float acc = 0.0f;
        if (f == 0) acc = wl1[o*80];               // filt[:,:,0] = x[:,:,0]
        else if (f < NB_) {
            for (int n = 1; n < 79; ++n) {         // fb rows 1..78 (row 79 zero)
                float bn = bs[n], bn1 = bs[n+1], bn2 = bs[n+2];
                int ibn  = (int)floorf(bn);
                int ibn1 = (int)floorf(bn1);
                int ibn2 = (int)floorf(bn2);
                float fbv = 0.0f;
                if (f >= ibn && f < ibn1) {
                    float d = (bn1-bn)*(bn1-bn);
                    fbv = ((float)f - bn) / (d > 0.0f ? d : 1.0f);
                } else if (f >= ibn1 && f < ibn2) {
                    float d = (bn2-bn1)*(bn2-bn1);
                    fbv = (bn2 - (float)f) / (d > 0.0f ? d : 1.0f);
                }
                acc += wl1[o*80 + n] * fbv;
            }
        }
        if (f == 256) wtail[o] = acc;              // fp32 rank-1 tail column
        ushort_t h = f2bf(acc);
        weh[gid] = h; wel[gid] = f2bf(acc - bf2f(h));
        return;
    }
    gid -= 64*320;
    if (gid < 3*128*64) {                          // conv1: [k][c][ci=64]
        int k = gid / (128*64), rem = gid % (128*64);
        int c = rem >> 6, ci = rem & 63;
        float v = wc1[(c*64 + ci)*3 + k];
        ushort_t h = f2bf(v);
        w1h[gid] = h; w1l[gid] = f2bf(v - bf2f(h));
        return;
    }
    gid -= 3*128*64;
    if (gid < 3*128*128) {                         // conv2: [k][c][ci=128]
        int k = gid / (128*128), rem = gid % (128*128);
        int c = rem >> 7, ci = rem & 127;
        float v = wc2[(c*128 + ci)*3 + k];
        ushort_t h = f2bf(v);
        w2h[gid] = h; w2l[gid] = f2bf(v - bf2f(h));
        return;
    }
    gid -= 3*128*128;
    if (gid < 3*128*128) {                         // conv3
        int k = gid / (128*128), rem = gid % (128*128);
        int c = rem >> 7, ci = rem & 127;
        float v = wc3[(c*128 + ci)*3 + k];
        ushort_t h = f2bf(v);
        w3h[gid] = h; w3l[gid] = f2bf(v - bf2f(h));
        return;
    }
    gid -= 3*128*128;
    if (gid < 64*128) {                            // wa1 [o=64][ci=128]
        float v = wa1[gid];
        ushort_t h = f2bf(v);
        wa1h[gid] = h; wa1l[gid] = f2bf(v - bf2f(h));
        return;
    }
    gid -= 64*128;
    if (gid < 128*64) {                            // wa2 [o=128][ci=64]
        float v = wa2[gid];
        ushort_t h = f2bf(v);
        wa2h[gid] = h; wa2l[gid] = f2bf(v - bf2f(h));
        return;
    }
}

// ---------------------------------------------------------------------------
// lin1: h[t][c] = relu( x[t][:257] . Weff[c][:] + b[c] ). 4 full K-chunks on
// MFMA (split-bf16 3-pass) + fp32 rank-1 tail (k=256) in epilogue. Register
// prefetch pipelines chunk c+1 loads under chunk c's MFMA (T14).
__launch_bounds__(256)
__global__ void lin1_mfma(const float* __restrict__ X,
                          const ushort_t* __restrict__ Wh, const ushort_t* __restrict__ Wl,
                          const float* __restrict__ wtail,
                          const float* __restrict__ bias, float* __restrict__ H) {
    __shared__ __align__(16) ushort_t ash[128*64];
    __shared__ __align__(16) ushort_t asl[128*64];
    __shared__ float xs[128];
    __shared__ float wts[64];
    const int tid  = threadIdx.x;
    const int lane = tid & 63;
    const int wid  = tid >> 6;
    const int wy   = wid >> 1, wx = wid & 1;
    const int l16  = lane & 15, l4 = lane >> 4;
    const int r0   = blockIdx.x * 128;

    if (tid < 128)       xs[tid] = X[(size_t)(r0 + tid)*NB_ + 256];
    else if (tid < 192)  wts[tid - 128] = wtail[tid - 128];

#define LIN1_LOAD(dst, k0)                                            \
    _Pragma("unroll")                                                 \
    for (int i = 0; i < 8; ++i) {                                     \
        int q = tid + i*256; int r = q >> 4, cc = (q & 15) << 2;      \
        dst[i] = *(const float4a*)(X + (size_t)(r0 + r)*NB_ + (k0) + cc); \
    }
#define LIN1_CW(src)                                                  \
    _Pragma("unroll")                                                 \
    for (int i = 0; i < 8; ++i) {                                     \
        int q = tid + i*256; int r = q >> 4, cc = (q & 15) << 2;      \
        uint2 ph, pl;                                                 \
        split_pack(src[i].x, src[i].y, src[i].z, src[i].w, ph, pl);   \
        unsigned byte = ((unsigned)(r*64 + cc))*2u ^ ((unsigned)((r & 7) << 4)); \
        *(uint2*)((char*)ash + byte) = ph;                            \
        *(uint2*)((char*)asl + byte) = pl;                            \
    }

    float4a bufA[8], bufB[8];
    LIN1_LOAD(bufA, 0);

    f32x4 acc[4][2];
    const f32x4 z = {0.f,0.f,0.f,0.f};
#pragma unroll
    for (int m = 0; m < 4; ++m) { acc[m][0] = z; acc[m][1] = z; }

#pragma unroll
    for (int ck = 0; ck < 4; ++ck) {
        const float4a* cur = (ck & 1) ? bufB : bufA;
        float4a*       nxt = (ck & 1) ? bufA : bufB;
        if (ck < 3) LIN1_LOAD(nxt, (ck + 1)*64);
        LIN1_CW(cur);
        __syncthreads();
#pragma unroll
        for (int kk = 0; kk < 64; kk += 32) {
            bf16x8 bh[2], bl[2];
#pragma unroll
            for (int n = 0; n < 2; ++n) {
                int c = wx*32 + n*16 + l16;
                size_t off = (size_t)c*320 + ck*64 + kk + l4*8;
                bh[n] = *(const bf16x8*)(Wh + off);
                bl[n] = *(const bf16x8*)(Wl + off);
            }
            bf16x8 fh[4], fl[4];
#pragma unroll
            for (int m = 0; m < 4; ++m) {
                int r = wy*64 + m*16 + l16;
                unsigned byte = ((unsigned)(r*64 + kk + l4*8))*2u ^ ((unsigned)((r & 7) << 4));
                fh[m] = *(const bf16x8*)((const char*)ash + byte);
                fl[m] = *(const bf16x8*)((const char*)asl + byte);
            }
#pragma unroll
            for (int m = 0; m < 4; ++m)
#pragma unroll
                for (int n = 0; n < 2; ++n) {
                    acc[m][n] = __builtin_amdgcn_mfma_f32_16x16x32_bf16(fh[m], bh[n], acc[m][n], 0, 0, 0);
                    acc[m][n] = __builtin_amdgcn_mfma_f32_16x16x32_bf16(fh[m], bl[n], acc[m][n], 0, 0, 0);
                    acc[m][n] = __builtin_amdgcn_mfma_f32_16x16x32_bf16(fl[m], bh[n], acc[m][n], 0, 0, 0);
                }
        }
        __syncthreads();
    }
#undef LIN1_LOAD
#undef LIN1_CW

#pragma unroll
    for (int m = 0; m < 4; ++m)
#pragma unroll
        for (int n = 0; n < 2; ++n) {
            int c = wx*32 + n*16 + l16;
            float bv = bias[c];
            float wc = wts[c];
            int rbl = wy*64 + m*16 + l4*4;
#pragma unroll
            for (int rg = 0; rg < 4; ++rg) {
                int rl = rbl + rg;
                float v = acc[m][n][rg] + bv + xs[rl]*wc;   // fp32 k=256 tail
                H[(size_t)(r0 + rl)*64 + c] = fmaxf(v, 0.0f);
            }
        }
}

// ---------------------------------------------------------------------------
// Dilated conv (K=3) via split-bf16 MFMA.
template<int CIN, int DIL, int RES>
__launch_bounds__(256)
__global__ void dconv_mfma(const float* __restrict__ X,
                           const ushort_t* __restrict__ Wh,
                           const ushort_t* __restrict__ Wl,
                           const float* __restrict__ bias, float* __restrict__ Y) {
    constexpr int TT = 128;
    constexpr int HS = TT + 2*DIL;
    __shared__ __align__(16) ushort_t hsh[HS*CIN];
    __shared__ __align__(16) ushort_t hsl[HS*CIN];

    const int tid  = threadIdx.x;
    const int lane = tid & 63;
    const int wid  = tid >> 6;
    const int wy   = wid >> 1;
    const int wx   = wid & 1;
    const int l16  = lane & 15;
    const int l4   = lane >> 4;
    const int t0   = blockIdx.x * TT;
    const int b    = blockIdx.y;

    for (int idx = tid; idx < HS*CIN/4; idx += 256) {
        int e  = idx << 2;
        int r  = e / CIN, ci = e % CIN;
        int t  = t0 - DIL + r;
        float4 v = make_float4(0.f, 0.f, 0.f, 0.f);
        if (t >= 0 && t < T_) v = *(const float4*)&X[((size_t)b*T_ + t)*CIN + ci];
        uint2 ph, pl;
        split_pack(v.x, v.y, v.z, v.w, ph, pl);
        unsigned byte = ((unsigned)(r*CIN + ci))*2u ^ ((unsigned)((r & 7) << 4));
        *(uint2*)((char*)hsh + byte) = ph;
        *(uint2*)((char*)hsl + byte) = pl;
    }
    __syncthreads();

    f32x4 acc[4][4];
    const f32x4 z = {0.f, 0.f, 0.f, 0.f};
#pragma unroll
    for (int m = 0; m < 4; ++m)
#pragma unroll
        for (int n = 0; n < 4; ++n) acc[m][n] = z;

    for (int k = 0; k < 3; ++k) {
#pragma unroll
        for (int cib = 0; cib < CIN; cib += 32) {
            bf16x8 bh[4], bl[4];
#pragma unroll
            for (int n = 0; n < 4; ++n) {
                int c = wx*64 + n*16 + l16;
                size_t off = ((size_t)(k*128 + c))*CIN + cib + l4*8;
                bh[n] = *(const bf16x8*)(Wh + off);
                bl[n] = *(const bf16x8*)(Wl + off);
            }
            bf16x8 ah[4], al[4];
#pragma unroll
            for (int m = 0; m < 4; ++m) {
                int r = wy*64 + m*16 + l16 + k*DIL;
                unsigned byte = ((unsigned)(r*CIN + cib + l4*8))*2u
                              ^ ((unsigned)((r & 7) << 4));
                ah[m] = *(const bf16x8*)((const char*)hsh + byte);
                al[m] = *(const bf16x8*)((const char*)hsl + byte);
            }
#pragma unroll
            for (int m = 0; m < 4; ++m)
#pragma unroll
                for (int n = 0; n < 4; ++n) {
                    acc[m][n] = __builtin_amdgcn_mfma_f32_16x16x32_bf16(ah[m], bh[n], acc[m][n], 0, 0, 0);
                    acc[m][n] = __builtin_amdgcn_mfma_f32_16x16x32_bf16(ah[m], bl[n], acc[m][n], 0, 0, 0);
                    acc[m][n] = __builtin_amdgcn_mfma_f32_16x16x32_bf16(al[m], bh[n], acc[m][n], 0, 0, 0);
                }
        }
    }

#pragma unroll
    for (int m = 0; m < 4; ++m) {
        int tl_base = wy*64 + m*16 + l4*4;
#pragma unroll
        for (int n = 0; n < 4; ++n) {
            int c = wx*64 + n*16 + l16;
            float bv = bias[c];
#pragma unroll
            for (int rg = 0; rg < 4; ++rg) {
                int tl = tl_base + rg;
                int t  = t0 + tl;
                if (t < T_) {
                    float v = acc[m][n][rg] + bv;
                    if (RES >= 1) {
                        int r = tl + DIL;
                        unsigned byte = ((unsigned)(r*CIN + c))*2u
                                      ^ ((unsigned)((r & 7) << 4));
                        float cen = bf2f(*(const ushort_t*)((const char*)hsh + byte))
                                  + bf2f(*(const ushort_t*)((const char*)hsl + byte));
                        v += (RES == 2) ? 2.0f*cen : cen;
                    }
                    Y[((size_t)b*T_ + t)*128 + c] = v;
                }
            }
        }
    }
}

// ---------------------------------------------------------------------------
// Fused ASP: v = tanh(i3 @ wa1^T + ba1); logits = v @ wa2^T + ba2 (stored);
// plus per-(b,chunk,c) online softmax partials (max, sumexp) over t.
__launch_bounds__(256)
__global__ void asp_fused(const float* __restrict__ I3,
                          const ushort_t* __restrict__ Wa1h, const ushort_t* __restrict__ Wa1l,
                          const ushort_t* __restrict__ Wa2h, const ushort_t* __restrict__ Wa2l,
                          const float* __restrict__ ba1, const float* __restrict__ ba2,
                          float* __restrict__ logits,
                          float* __restrict__ pm, float* __restrict__ ps) {
    __shared__ __align__(16) ushort_t ah_[128*64];
    __shared__ __align__(16) ushort_t al_[128*64];
    __shared__ __align__(16) ushort_t vh_[128*64];
    __shared__ __align__(16) ushort_t vl_[128*64];
    __shared__ float redM[2][128];
    __shared__ float redS[2][128];

    const int tid  = threadIdx.x;
    const int lane = tid & 63;
    const int wid  = tid >> 6;
    const int wy   = wid >> 1, wx = wid & 1;
    const int l16  = lane & 15, l4 = lane >> 4;
    const int ch   = blockIdx.x;
    const int b    = blockIdx.y;
    const int t0   = ch * CHL;

    // ---- stage 1: v = tanh(i3 @ wa1^T + ba1), K=128 in 2 chunks ----
    f32x4 acc1[4][2];
    const f32x4 z = {0.f,0.f,0.f,0.f};
#pragma unroll
    for (int m = 0; m < 4; ++m) { acc1[m][0] = z; acc1[m][1] = z; }

    for (int k0 = 0; k0 < 128; k0 += 64) {
        __syncthreads();
        for (int q = tid; q < 2048; q += 256) {
            int r = q >> 4, qq = (q & 15) << 2;
            int t = t0 + r;
            float4 v = make_float4(0.f,0.f,0.f,0.f);
            if (t < T_) v = *(const float4*)&I3[((size_t)b*T_ + t)*128 + k0 + qq];
            uint2 ph, pl;
            split_pack(v.x, v.y, v.z, v.w, ph, pl);
            unsigned byte = ((unsigned)(r*64 + qq))*2u ^ ((unsigned)((r & 7) << 4));
            *(uint2*)((char*)ah_ + byte) = ph;
            *(uint2*)((char*)al_ + byte) = pl;
        }
        __syncthreads();
#pragma unroll
        for (int kk = 0; kk < 64; kk += 32) {
            bf16x8 bh[2], bl[2];
#pragma unroll
            for (int n = 0; n < 2; ++n) {
                int c = wx*32 + n*16 + l16;
                size_t off = (size_t)c*128 + k0 + kk + l4*8;
                bh[n] = *(const bf16x8*)(Wa1h + off);
                bl[n] = *(const bf16x8*)(Wa1l + off);
            }
            bf16x8 fh[4], fl[4];
#pragma unroll
            for (int m = 0; m < 4; ++m) {
                int r = wy*64 + m*16 + l16;
                unsigned byte = ((unsigned)(r*64 + kk + l4*8))*2u ^ ((unsigned)((r & 7) << 4));
                fh[m] = *(const bf16x8*)((const char*)ah_ + byte);
                fl[m] = *(const bf16x8*)((const char*)al_ + byte);
            }
#pragma unroll
            for (int m = 0; m < 4; ++m)
#pragma unroll
                for (int n = 0; n < 2; ++n) {
                    acc1[m][n] = __builtin_amdgcn_mfma_f32_16x16x32_bf16(fh[m], bh[n], acc1[m][n], 0, 0, 0);
                    acc1[m][n] = __builtin_amdgcn_mfma_f32_16x16x32_bf16(fh[m], bl[n], acc1[m][n], 0, 0, 0);
                    acc1[m][n] = __builtin_amdgcn_mfma_f32_16x16x32_bf16(fl[m], bh[n], acc1[m][n], 0, 0, 0);
                }
        }
    }
    // epilogue 1: tanh, write v (t x 64) to LDS bf16 hi/lo
#pragma unroll
    for (int m = 0; m < 4; ++m)
#pragma unroll
        for (int n = 0; n < 2; ++n) {
            int c = wx*32 + n*16 + l16;
            float bv = ba1[c];
            int rb = wy*64 + m*16 + l4*4;
#pragma unroll
            for (int rg = 0; rg < 4; ++rg) {
                float v = tanhf(acc1[m][n][rg] + bv);
                int r = rb + rg;
                unsigned byte = ((unsigned)(r*64 + c))*2u ^ ((unsigned)((r & 7) << 4));
                ushort_t h = f2bf(v);
                *(ushort_t*)((char*)vh_ + byte) = h;
                *(ushort_t*)((char*)vl_ + byte) = f2bf(v - bf2f(h));
            }
        }
    __syncthreads();

    // ---- stage 2: D[n][t] = sum_k wa2[n][k] v[t][k] + ba2[n] ----
    f32x4 acc2[4][4];
#pragma unroll
    for (int m = 0; m < 4; ++m)
#pragma unroll
        for (int j = 0; j < 4; ++j) acc2[m][j] = z;

#pragma unroll
    for (int kk = 0; kk < 64; kk += 32) {
        bf16x8 awh[4], awl[4];
#pragma unroll
        for (int m = 0; m < 4; ++m) {
            int n = wy*64 + m*16 + l16;
            size_t off = (size_t)n*64 + kk + l4*8;
            awh[m] = *(const bf16x8*)(Wa2h + off);
            awl[m] = *(const bf16x8*)(Wa2l + off);
        }
        bf16x8 bvh[4], bvl[4];
#pragma unroll
        for (int j = 0; j < 4; ++j) {
            int r = wx*64 + j*16 + l16;
            unsigned byte = ((unsigned)(r*64 + kk + l4*8))*2u ^ ((unsigned)((r & 7) << 4));
            bvh[j] = *(const bf16x8*)((const char*)vh_ + byte);
            bvl[j] = *(const bf16x8*)((const char*)vl_ + byte);
        }
#pragma unroll
        for (int m = 0; m < 4; ++m)
#pragma unroll
            for (int j = 0; j < 4; ++j) {
                acc2[m][j] = __builtin_amdgcn_mfma_f32_16x16x32_bf16(awh[m], bvh[j], acc2[m][j], 0, 0, 0);
                acc2[m][j] = __builtin_amdgcn_mfma_f32_16x16x32_bf16(awh[m], bvl[j], acc2[m][j], 0, 0, 0);
                acc2[m][j] = __builtin_amdgcn_mfma_f32_16x16x32_bf16(awl[m], bvh[j], acc2[m][j], 0, 0, 0);
            }
    }

    // epilogue 2: bias add, store logits (t-major), softmax partials over t
#pragma unroll
    for (int m = 0; m < 4; ++m) {
        const float4 bv = *(const float4*)&ba2[wy*64 + m*16 + l4*4];
#pragma unroll
        for (int j = 0; j < 4; ++j) {
            acc2[m][j][0] += bv.x; acc2[m][j][1] += bv.y;
            acc2[m][j][2] += bv.z; acc2[m][j][3] += bv.w;
        }
    }
#pragma unroll
    for (int j = 0; j < 4; ++j) {
        int tg = t0 + wx*64 + j*16 + l16;
        if (tg < T_) {
#pragma unroll
            for (int m = 0; m < 4; ++m) {
                float4 o = make_float4(acc2[m][j][0], acc2[m][j][1], acc2[m][j][2], acc2[m][j][3]);
                *(float4*)&logits[((size_t)b*T_ + tg)*128 + wy*64 + m*16 + l4*4] = o;
            }
        }
    }
#pragma unroll
    for (int m = 0; m < 4; ++m)
#pragma unroll
        for (int rg = 0; rg < 4; ++rg) {
            int n = wy*64 + m*16 + l4*4 + rg;
            float mx = -INFINITY;
#pragma unroll
            for (int j = 0; j < 4; ++j) {
                int tg = t0 + wx*64 + j*16 + l16;
                if (tg < T_) mx = fmaxf(mx, acc2[m][j][rg]);
            }
            mx = fmaxf(mx, __shfl_xor(mx, 1));
            mx = fmaxf(mx, __shfl_xor(mx, 2));
            mx = fmaxf(mx, __shfl_xor(mx, 4));
            mx = fmaxf(mx, __shfl_xor(mx, 8));
            float se = 0.0f;
#pragma unroll
            for (int j = 0; j < 4; ++j) {
                int tg = t0 + wx*64 + j*16 + l16;
                if (tg < T_) se += expf(acc2[m][j][rg] - mx);
            }
            se += __shfl_xor(se, 1);
            se += __shfl_xor(se, 2);
            se += __shfl_xor(se, 4);
            se += __shfl_xor(se, 8);
            if (l16 == 0) { redM[wx][n] = mx; redS[wx][n] = se; }
        }
    __syncthreads();
    if (tid < 128) {
        float m0 = redM[0][tid], m1 = redM[1][tid];
        float M  = fmaxf(m0, m1);
        float S  = 0.0f;
        if (m0 > -INFINITY) S += redS[0][tid] * expf(m0 - M);
        if (m1 > -INFINITY) S += redS[1][tid] * expf(m1 - M);
        pm[((size_t)b*NCH + ch)*128 + tid] = M;
        ps[((size_t)b*NCH + ch)*128 + tid] = S;
    }
}

// ---------------------------------------------------------------------------
__global__ void sm_pass_b(const float* __restrict__ pm, const float* __restrict__ ps,
                          float* __restrict__ Ms, float* __restrict__ Ss) {
    const int c = threadIdx.x, b = blockIdx.x;
    float M = -INFINITY;
    for (int ch = 0; ch < NCH; ++ch) M = fmaxf(M, pm[((size_t)b*NCH + ch)*128 + c]);
    float S = 0.0f;
    for (int ch = 0; ch < NCH; ++ch) {
        float m = pm[((size_t)b*NCH + ch)*128 + c];
        if (m > -INFINITY) S += ps[((size_t)b*NCH + ch)*128 + c] * expf(m - M);
    }
    Ms[b*128 + c] = M;
    Ss[b*128 + c] = S;
}

// weighted stats partials: vectorized float4 stream of logits+i3 (196 MB)
__launch_bounds__(256)
__global__ void sm_pass_c(const float* __restrict__ logits, const float* __restrict__ i3,
                          const float* __restrict__ Ms, float* __restrict__ pcm,
                          float* __restrict__ pcq) {
    __shared__ float redm[8*128];
    __shared__ float redq[8*128];
    const int tid = threadIdx.x;
    const int ch  = blockIdx.x, b = blockIdx.y;
    const int c4  = (tid & 31) * 4;
    const int tr  = tid >> 5;                     // 0..7
    const int ts  = ch * CHL, te = min(T_, ts + CHL);
    const float4 M = *(const float4*)&Ms[b*128 + c4];
    float4 am = make_float4(0.f,0.f,0.f,0.f);
    float4 aq = make_float4(0.f,0.f,0.f,0.f);
    for (int t = ts + tr; t < te; t += 8) {
        const float4 a = *(const float4*)&logits[((size_t)b*T_ + t)*128 + c4];
        const float4 x = *(const float4*)&i3[((size_t)b*T_ + t)*128 + c4];
        float p0 = expf(a.x - M.x), p1 = expf(a.y - M.y);
        float p2 = expf(a.z - M.z), p3 = expf(a.w - M.w);
        am.x += p0*x.x; aq.x += p0*x.x*x.x;
        am.y += p1*x.y; aq.y += p1*x.y*x.y;
        am.z += p2*x.z; aq.z += p2*x.z*x.z;
        am.w += p3*x.w; aq.w += p3*x.w*x.w;
    }
    *(float4*)&redm[tr*128 + c4] = am;
    *(float4*)&redq[tr*128 + c4] = aq;
    __syncthreads();
    if (tid < 128) {
        float sm = 0.f, sq = 0.f;
#pragma unroll
        for (int k = 0; k < 8; ++k) { sm += redm[k*128 + tid]; sq += redq[k*128 + tid]; }
        pcm[((size_t)b*NCH + ch)*128 + tid] = sm;
        pcq[((size_t)b*NCH + ch)*128 + tid] = sq;
    }
}

// stats -> layernorm(256) -> linear 256->512
__global__ void final_kernel(const float* __restrict__ pcm, const float* __restrict__ pcq,
                             const float* __restrict__ Ss, const float* __restrict__ gamma,
                             const float* __restrict__ beta, const float* __restrict__ w2,
                             const float* __restrict__ b2, float* __restrict__ out) {
    __shared__ float row[256];
    __shared__ float nrm[256];
    __shared__ float red[8];
    const int tid = threadIdx.x, b = blockIdx.x;
    if (tid < 128) {
        float sm = 0.0f, sq = 0.0f;
        for (int ch = 0; ch < NCH; ++ch) {
            sm += pcm[((size_t)b*NCH + ch)*128 + tid];
            sq += pcq[((size_t)b*NCH + ch)*128 + tid];
        }
        float S = Ss[b*128 + tid];
        float mean = sm / S;
        float q    = sq / S;
        float resid = q - mean*mean;
        float stdv  = sqrtf(fmaxf(resid, 1e-9f));
        row[tid]       = mean;
        row[128 + tid] = stdv;
    }
    __syncthreads();
    float v  = row[tid];
    float s1 = v, s2 = v*v;
    for (int off = 32; off >= 1; off >>= 1) {
        s1 += __shfl_down(s1, off, 64);
        s2 += __shfl_down(s2, off, 64);
    }
    if ((tid & 63) == 0) { red[tid >> 6] = s1; red[4 + (tid >> 6)] = s2; }
    __syncthreads();
    float S1 = red[0] + red[1] + red[2] + red[3];
    float S2 = red[4] + red[5] + red[6] + red[7];
    float mu  = S1 / 256.0f;
    float var = S2 / 256.0f - mu*mu;
    float inv = 1.0f / sqrtf(var + 1e-5f);
    nrm[tid] = (v - mu)*inv*gamma[tid] + beta[tid];
    __syncthreads();
#pragma unroll
    for (int oo = 0; oo < 2; ++oo) {
        int o = tid + oo*256;
        float acc = b2[o];
        const float4* wr = (const float4*)&w2[(size_t)o*256];
        for (int j = 0; j < 64; ++j) {
            float4 w = wr[j];
            acc += w.x*nrm[j*4] + w.y*nrm[j*4+1] + w.z*nrm[j*4+2] + w.w*nrm[j*4+3];
        }
        out[(size_t)b*512 + o] = acc;
    }
}

// ---------------------------------------------------------------------------
extern "C" void kernel_launch(void* const* d_in, const int* in_sizes, int n_in,
                              void* d_out, int out_size, void* d_ws, size_t ws_size,
                              hipStream_t stream) {
    const float* x      = (const float*)d_in[0];
    const float* bp     = (const float*)d_in[1];
    const float* w_lin1 = (const float*)d_in[2];
    const float* b_lin1 = (const float*)d_in[3];
    const float* wc1    = (const float*)d_in[4];
    const float* bc1    = (const float*)d_in[5];
    const float* wc2    = (const float*)d_in[6];
    const float* bc2    = (const float*)d_in[7];
    const float* wc3    = (const float*)d_in[8];
    const float* bc3    = (const float*)d_in[9];
    const float* wa1    = (const float*)d_in[10];
    const float* ba1    = (const float*)d_in[11];
    const float* wa2    = (const float*)d_in[12];
    const float* ba2    = (const float*)d_in[13];
    const float* gamma  = (const float*)d_in[14];
    const float* beta   = (const float*)d_in[15];
    const float* wl2    = (const float*)d_in[16];
    const float* bl2    = (const float*)d_in[17];

    float* ws   = (float*)d_ws;
    float* bs   = ws + OFF_BS;
    ushort_t* weh  = (ushort_t*)(ws + OFF_WEFF);
    ushort_t* wel  = weh + 64*320;
    float* wtail   = ws + OFF_WTAIL;
    ushort_t* w1h  = (ushort_t*)(ws + OFF_W1);
    ushort_t* w1l  = w1h + 3*128*64;
    ushort_t* w2h  = (ushort_t*)(ws + OFF_W2);
    ushort_t* w2l  = w2h + 3*128*128;
    ushort_t* w3h  = (ushort_t*)(ws + OFF_W3);
    ushort_t* w3l  = w3h + 3*128*128;
    ushort_t* wa1h = (ushort_t*)(ws + OFF_WA1);
    ushort_t* wa1l = wa1h + 64*128;
    ushort_t* wa2h = (ushort_t*)(ws + OFF_WA2);
    ushort_t* wa2l = wa2h + 128*64;
    float* pm   = ws + OFF_PM;
    float* ps   = ws + OFF_PS;
    float* Ms   = ws + OFF_MS;
    float* Ss   = ws + OFF_SS;
    float* pcm  = ws + OFF_PCM;
    float* pcq  = ws + OFF_PCQ;
    float* h    = ws + OFF_H;
    float* bufA = ws + OFF_A;    // i1, then i3
    float* bufB = ws + OFF_BB;   // s,  then logits

    sort_kernel<<<dim3(1), dim3(64), 0, stream>>>(bp, bs);
    prep_kernel<<<dim3(624), dim3(256), 0, stream>>>(bs, w_lin1, wc1, wc2, wc3, wa1, wa2,
                                                     weh, wel, wtail, w1h, w1l, w2h, w2l,
                                                     w3h, w3l, wa1h, wa1l, wa2h, wa2l);
    // h = relu(x @ Weff^T + b_lin1)
    lin1_mfma<<<dim3(R_/128), dim3(256), 0, stream>>>(x, weh, wel, wtail, b_lin1, h);
    // i1 = conv1(h) + b
    dconv_mfma<64, 2, 0><<<dim3(24, B_), dim3(256), 0, stream>>>(h, w1h, w1l, bc1, bufA);
    // s = i1 + i2 = conv2(i1) + b + 2*i1
    dconv_mfma<128, 3, 2><<<dim3(24, B_), dim3(256), 0, stream>>>(bufA, w2h, w2l, bc2, bufB);
    // i3 = conv3(s) + b + s
    dconv_mfma<128, 4, 1><<<dim3(24, B_), dim3(256), 0, stream>>>(bufB, w3h, w3l, bc3, bufA);
    // fused asp1+asp2+softmax partials (logits into bufB)
    asp_fused<<<dim3(NCH, B_), dim3(256), 0, stream>>>(bufA, wa1h, wa1l, wa2h, wa2l,
                                                       ba1, ba2, bufB, pm, ps);
    sm_pass_b<<<dim3(B_), dim3(128), 0, stream>>>(pm, ps, Ms, Ss);
    sm_pass_c<<<dim3(NCH, B_), dim3(256), 0, stream>>>(bufB, bufA, Ms, pcm, pcq);
    final_kernel<<<dim3(B_), dim3(256), 0, stream>>>(pcm, pcq, Ss, gamma, beta, wl2, bl2,
                                                     (float*)d_out);
}